// Round 6
// baseline (380.001 us; speedup 1.0000x reference)
//
#include <hip/hip_runtime.h>
#include <hip/hip_bf16.h>
#include <math.h>

// Problem constants (from reference)
#define N_NODES 50000
#define N_EDGES 800000
#define E_TOT   (N_EDGES + N_NODES)   // edges + self loops = 850000
#define HID     128
#define N_GRAPHS 64
#define NEG_SLOPE 0.2f

// Radix partition params
#define NBKT 196                      // buckets of 256 dst nodes
#define CAPB 6144                     // fixed bucket capacity (mean 4337, +27 sigma)
#define CHUNK3 4096
#define NB3  ((E_TOT + CHUNK3 - 1) / CHUNK3)    // 208
#define NB_BOUNDS ((N_NODES + 255) / 256)       // 196

typedef __attribute__((ext_vector_type(8))) short bf16x8;
typedef __attribute__((ext_vector_type(4))) float f32x4;

__device__ __forceinline__ ushort f2bf(float f) {
    union { float f; uint u; } x; x.f = f;
    uint r = x.u + 0x7fffu + ((x.u >> 16) & 1u);   // round-to-nearest-even
    return (ushort)(r >> 16);
}
__device__ __forceinline__ float bfbits2f(uint bits_hi) {
    union { uint u; float f; } x; x.u = bits_hi;
    return x.f;
}

// ---------------------------------------------------------------------------
// Prep: convert+transpose both weight matrices, zero gcur. One dispatch.
// ---------------------------------------------------------------------------
__global__ __launch_bounds__(256) void prep(const float* __restrict__ W1,
                                            const float* __restrict__ W2,
                                            ushort* __restrict__ Wt1,
                                            ushort* __restrict__ Wt2,
                                            int* __restrict__ gcur) {
    int idx = blockIdx.x * 256 + threadIdx.x;
    if (idx < 256 * 128) {
        int k = idx >> 7, n = idx & 127;
        Wt1[n * 256 + k] = f2bf(W1[idx]);
    } else if (idx < 256 * 128 + 128 * 128) {
        int j = idx - 256 * 128;
        int k = j >> 7, n = j & 127;
        Wt2[n * 128 + k] = f2bf(W2[j]);
    }
    if (idx <= NBKT) gcur[idx] = 0;
}

// ---------------------------------------------------------------------------
// P3: block-local bucket ordering in LDS, coalesced run writes into
// fixed-capacity bucket slots. val = bucket(8) | src(16) | dst&255 (8).
// ---------------------------------------------------------------------------
__global__ __launch_bounds__(256) void bin_scatter(const int* __restrict__ edge_src,
                                                   const int* __restrict__ edge_dst,
                                                   int* __restrict__ gcur,
                                                   uint* __restrict__ staged) {
    __shared__ int hist[256], scan_s[256], base_l[256], cur[256], runbase[256];
    __shared__ uint vals[CHUNK3];
    int tid = threadIdx.x;
    int e0 = blockIdx.x * CHUNK3;
    int cnt = min(CHUNK3, E_TOT - e0);

    hist[tid] = 0;
    __syncthreads();
    for (int i = tid; i < cnt; i += 256) {
        int e = e0 + i;
        int d = (e < N_EDGES) ? edge_dst[e] : (e - N_EDGES);
        atomicAdd(&hist[d >> 8], 1);
    }
    __syncthreads();
    int v = hist[tid];
    scan_s[tid] = v;
    __syncthreads();
    for (int off = 1; off < 256; off <<= 1) {
        int t = (tid >= off) ? scan_s[tid - off] : 0;
        __syncthreads();
        scan_s[tid] += t;
        __syncthreads();
    }
    base_l[tid] = scan_s[tid] - v;
    cur[tid] = scan_s[tid] - v;
    __syncthreads();
    for (int i = tid; i < cnt; i += 256) {
        int e = e0 + i;
        int s, d;
        if (e < N_EDGES) { s = edge_src[e]; d = edge_dst[e]; }
        else             { s = d = e - N_EDGES; }
        int p = atomicAdd(&cur[d >> 8], 1);
        vals[p] = ((uint)(d >> 8) << 24) | ((uint)s << 8) | (uint)(d & 255);
    }
    __syncthreads();
    if (tid < NBKT && hist[tid] > 0) runbase[tid] = atomicAdd(&gcur[tid], hist[tid]);
    __syncthreads();
    for (int i = tid; i < cnt; i += 256) {
        uint v2 = vals[i];
        int b = (int)(v2 >> 24);
        int idx = runbase[b] + (i - base_l[b]);
        if (idx < CAPB) staged[b * CAPB + idx] = v2;
    }
}

// ---------------------------------------------------------------------------
// Fused: block NB_BOUNDS does the bucket scan; blocks 0..NB_BOUNDS-1 do
// graph boundaries from sorted batch array.
// ---------------------------------------------------------------------------
__global__ __launch_bounds__(256) void scan_bounds(const int* __restrict__ gcur,
                                                   int* __restrict__ bbase,
                                                   int* __restrict__ row_start,
                                                   const int* __restrict__ batch,
                                                   int* __restrict__ gstart) {
    int tid = threadIdx.x;
    if (blockIdx.x == NB_BOUNDS) {
        __shared__ int s[256];
        int v = (tid < NBKT) ? gcur[tid] : 0;
        s[tid] = v;
        __syncthreads();
        for (int off = 1; off < 256; off <<= 1) {
            int t = (tid >= off) ? s[tid - off] : 0;
            __syncthreads();
            s[tid] += t;
            __syncthreads();
        }
        if (tid < NBKT) bbase[tid] = s[tid] - v;
        if (tid == 255) { bbase[NBKT] = s[255]; row_start[N_NODES] = s[255]; }
    } else {
        int i = blockIdx.x * 256 + tid;
        if (i >= N_NODES) return;
        int b  = batch[i];
        int bp = (i == 0) ? -1 : batch[i - 1];
        for (int g = bp + 1; g <= b; g++) gstart[g] = i;
        if (i == N_NODES - 1) {
            for (int g = b + 1; g <= N_GRAPHS; g++) gstart[g] = N_NODES;
        }
    }
}

// ---------------------------------------------------------------------------
// P4: one block per bucket; exact per-node CSR (ushort src) + row_start
// ---------------------------------------------------------------------------
__global__ __launch_bounds__(256) void bucket_build(const uint* __restrict__ staged,
                                                    const int* __restrict__ bbase,
                                                    int* __restrict__ row_start,
                                                    ushort* __restrict__ csr_src) {
    __shared__ int hist[256], scan_s[256], base_l[256];
    __shared__ uint lv[CAPB];
    int tid = threadIdx.x;
    int b = blockIdx.x;
    int base = bbase[b];
    int cnt = bbase[b + 1] - base;

    hist[tid] = 0;
    __syncthreads();
    for (int i = tid; i < cnt; i += 256) {
        uint v = staged[b * CAPB + i];
        lv[i] = v;
        atomicAdd(&hist[v & 255], 1);
    }
    __syncthreads();
    int v0 = hist[tid];
    scan_s[tid] = v0;
    __syncthreads();
    for (int off = 1; off < 256; off <<= 1) {
        int t = (tid >= off) ? scan_s[tid - off] : 0;
        __syncthreads();
        scan_s[tid] += t;
        __syncthreads();
    }
    int excl = scan_s[tid] - v0;
    base_l[tid] = excl;
    int node = b * 256 + tid;
    if (node < N_NODES) row_start[node] = base + excl;
    __syncthreads();
    for (int i = tid; i < cnt; i += 256) {
        uint v = lv[i];
        int pos = base + atomicAdd(&base_l[v & 255], 1);
        csr_src[pos] = (ushort)((v >> 8) & 0xFFFFu);
    }
}

// ---------------------------------------------------------------------------
// BF16 MFMA GEMM + fused alpha epilogue.
// ---------------------------------------------------------------------------
template <int K, bool ABF>
__global__ __launch_bounds__(256) void gemm_mfma(const void* __restrict__ Aptr,
                                                 const ushort* __restrict__ Wt,
                                                 ushort* __restrict__ Cbf,
                                                 const float* __restrict__ a_sv,
                                                 const float* __restrict__ a_dv,
                                                 float* __restrict__ alpha_s,
                                                 float* __restrict__ alpha_d, int M) {
    constexpr int KC = 64;
    constexpr int AP = 72;
    __shared__ ushort As[64 * AP];
    __shared__ ushort Bs[128 * AP];

    int tid = threadIdx.x;
    int lane = tid & 63;
    int wv = tid >> 6;
    int mrow = lane & 15;
    int quad = lane >> 4;
    int row0 = blockIdx.x * 64;

    f32x4 acc[8];
#pragma unroll
    for (int t = 0; t < 8; t++) acc[t] = (f32x4){0.f, 0.f, 0.f, 0.f};

    for (int k0 = 0; k0 < K; k0 += KC) {
        if constexpr (!ABF) {
            const float* A = (const float*)Aptr;
#pragma unroll
            for (int p = 0; p < 2; p++) {
                int c = p * 256 + tid;
                int r = c >> 3;
                int kk = (c & 7) * 8;
                int grow = row0 + r;
                float4 v0 = make_float4(0.f, 0.f, 0.f, 0.f);
                float4 v1 = v0;
                if (grow < M) {
                    const float* src = &A[(size_t)grow * K + k0 + kk];
                    v0 = *(const float4*)src;
                    v1 = *(const float4*)(src + 4);
                }
                uint4 w;
                w.x = (uint)f2bf(v0.x) | ((uint)f2bf(v0.y) << 16);
                w.y = (uint)f2bf(v0.z) | ((uint)f2bf(v0.w) << 16);
                w.z = (uint)f2bf(v1.x) | ((uint)f2bf(v1.y) << 16);
                w.w = (uint)f2bf(v1.z) | ((uint)f2bf(v1.w) << 16);
                *(uint4*)&As[r * AP + kk] = w;
            }
        } else {
            const ushort* A = (const ushort*)Aptr;
#pragma unroll
            for (int p = 0; p < 2; p++) {
                int c = p * 256 + tid;
                int r = c >> 3;
                int kk = (c & 7) * 8;
                int grow = row0 + r;
                uint4 v = make_uint4(0, 0, 0, 0);
                if (grow < M) v = *(const uint4*)&A[(size_t)grow * K + k0 + kk];
                *(uint4*)&As[r * AP + kk] = v;
            }
        }
#pragma unroll
        for (int p = 0; p < 4; p++) {
            int c = p * 256 + tid;
            int n = c >> 3;
            int kk = (c & 7) * 8;
            uint4 v = *(const uint4*)&Wt[(size_t)n * K + k0 + kk];
            *(uint4*)&Bs[n * AP + kk] = v;
        }
        __syncthreads();

        const ushort* arow = &As[(wv * 16 + mrow) * AP + quad * 8];
        const ushort* brow = &Bs[mrow * AP + quad * 8];
#pragma unroll
        for (int ks = 0; ks < KC; ks += 32) {
            bf16x8 a = *(const bf16x8*)&arow[ks];
#pragma unroll
            for (int t = 0; t < 8; t++) {
                bf16x8 b = *(const bf16x8*)&brow[t * 16 * AP + ks];
                acc[t] = __builtin_amdgcn_mfma_f32_16x16x32_bf16(a, b, acc[t], 0, 0, 0);
            }
        }
        __syncthreads();
    }

    // Fused alpha epilogue
    float as_r[8], ad_r[8];
#pragma unroll
    for (int t = 0; t < 8; t++) {
        int col = t * 16 + mrow;
        as_r[t] = a_sv[col];
        ad_r[t] = a_dv[col];
    }
#pragma unroll
    for (int r = 0; r < 4; r++) {
        float ps = 0.f, pd = 0.f;
#pragma unroll
        for (int t = 0; t < 8; t++) {
            ps = fmaf(acc[t][r], as_r[t], ps);
            pd = fmaf(acc[t][r], ad_r[t], pd);
        }
#pragma unroll
        for (int o = 1; o < 16; o <<= 1) {
            ps += __shfl_xor(ps, o, 64);
            pd += __shfl_xor(pd, o, 64);
        }
        int row = row0 + wv * 16 + quad * 4 + r;
        if (mrow == 0 && row < M) {
            alpha_s[row] = ps;
            alpha_d[row] = pd;
        }
    }

    // C write (C/D layout: col=lane&15, row=quad*4+reg)
#pragma unroll
    for (int t = 0; t < 8; t++) {
#pragma unroll
        for (int r = 0; r < 4; r++) {
            int row = row0 + wv * 16 + quad * 4 + r;
            if (row < M)
                Cbf[(size_t)row * HID + t * 16 + mrow] = f2bf(acc[t][r]);
        }
    }
}

// ---------------------------------------------------------------------------
// GAT aggregation, feature-blocked: each dispatch aggregates a 64-col half
// (working set 6.4 MB -> better per-XCD L2 hit rate). Pass A (CC=true)
// computes normalized softmax coefs (stored to coefbuf); pass B reloads them.
// 4 nodes/block, one wave/node; quarter-wave per edge (16 lanes x uint2 =
// 128 B = 64 cols), batch-4 -> 16 loads in flight per wave.
// ---------------------------------------------------------------------------
template <int COL0, bool CC>
__global__ __launch_bounds__(256) void gat_agg_half(const ushort* __restrict__ hbf,
                                                    const float* __restrict__ alpha_s,
                                                    const float* __restrict__ alpha_d,
                                                    const int* __restrict__ row_start,
                                                    const ushort* __restrict__ csr_src,
                                                    float* __restrict__ coefbuf,
                                                    const float* __restrict__ bias,
                                                    ushort* __restrict__ outbf) {
    __shared__ float coefs[4][64];
    __shared__ uint  soffs[4][64];
    int wv = threadIdx.x >> 6;
    int lane = threadIdx.x & 63;
    int n = blockIdx.x * 4 + wv;       // grid = N_NODES/4 exactly
    float* coef = coefs[wv];
    uint*  soff = soffs[wv];

    int beg = row_start[n];
    int deg = row_start[n + 1] - beg;

    float inv = 0.f, ex0 = 0.f, adn = 0.f;
    int s0r = 0;
    if (CC) {
        adn = alpha_d[n];
        if (lane < deg) {
            s0r = csr_src[beg + lane];
            float e = alpha_s[s0r] + adn;
            e = (e > 0.f) ? e : e * NEG_SLOPE;
            ex0 = __expf(e);
        }
        float ssum = ex0;
        for (int k = 64 + lane; k < deg; k += 64) {
            int s = csr_src[beg + k];
            float e = alpha_s[s] + adn;
            e = (e > 0.f) ? e : e * NEG_SLOPE;
            ssum += __expf(e);
        }
        for (int o = 32; o; o >>= 1) ssum += __shfl_xor(ssum, o, 64);
        inv = 1.f / ssum;
    }

    int q = lane >> 4;             // edge slot 0..3
    int c4 = (lane & 15) * 4;      // col offset within this 64-col half
    float a0 = 0.f, a1 = 0.f, a2 = 0.f, a3 = 0.f;
    const char* hbase = (const char*)hbf + (COL0 + c4) * 2;

    for (int c0 = 0; c0 < deg; c0 += 64) {
        int k = c0 + lane;
        if (k < deg) {
            float cf; uint so;
            if (CC) {
                if (c0 == 0) { cf = ex0 * inv; so = (uint)s0r * (HID * 2); }
                else {
                    int s = csr_src[beg + k];
                    float e = alpha_s[s] + adn;
                    e = (e > 0.f) ? e : e * NEG_SLOPE;
                    cf = __expf(e) * inv;
                    so = (uint)s * (HID * 2);
                }
                coefbuf[beg + k] = cf;
            } else {
                cf = coefbuf[beg + k];
                so = (uint)csr_src[beg + k] * (HID * 2);
            }
            coef[lane] = cf;
            soff[lane] = so;
        }
        __builtin_amdgcn_wave_barrier();
        int cnt = min(64, deg - c0);
        int T = (cnt - q + 3) >> 2;    // edges j = 4t+q < cnt
        int t = 0;
        for (; t + 4 <= T; t += 4) {
            float w[4]; uint off[4]; uint2 v[4];
#pragma unroll
            for (int b = 0; b < 4; b++) {
                int j = 4 * (t + b) + q;
                w[b] = coef[j];
                off[b] = soff[j];
            }
#pragma unroll
            for (int b = 0; b < 4; b++)
                v[b] = *(const uint2*)(hbase + off[b]);
#pragma unroll
            for (int b = 0; b < 4; b++) {
                a0 = fmaf(w[b], bfbits2f(v[b].x << 16), a0);
                a1 = fmaf(w[b], bfbits2f(v[b].x & 0xffff0000u), a1);
                a2 = fmaf(w[b], bfbits2f(v[b].y << 16), a2);
                a3 = fmaf(w[b], bfbits2f(v[b].y & 0xffff0000u), a3);
            }
        }
        for (; t < T; t++) {
            int j = 4 * t + q;
            float w = coef[j];
            uint2 v = *(const uint2*)(hbase + soff[j]);
            a0 = fmaf(w, bfbits2f(v.x << 16), a0);
            a1 = fmaf(w, bfbits2f(v.x & 0xffff0000u), a1);
            a2 = fmaf(w, bfbits2f(v.y << 16), a2);
            a3 = fmaf(w, bfbits2f(v.y & 0xffff0000u), a3);
        }
        __builtin_amdgcn_wave_barrier();
    }

    // Merge quarters, bias + ReLU, bf16 write (16 lanes x 8B per node-half)
    a0 += __shfl_xor(a0, 16, 64); a1 += __shfl_xor(a1, 16, 64);
    a2 += __shfl_xor(a2, 16, 64); a3 += __shfl_xor(a3, 16, 64);
    a0 += __shfl_xor(a0, 32, 64); a1 += __shfl_xor(a1, 32, 64);
    a2 += __shfl_xor(a2, 32, 64); a3 += __shfl_xor(a3, 32, 64);
    if (q == 0) {
        float4 bv = *(const float4*)&bias[COL0 + c4];
        float o0 = fmaxf(a0 + bv.x, 0.f);
        float o1 = fmaxf(a1 + bv.y, 0.f);
        float o2 = fmaxf(a2 + bv.z, 0.f);
        float o3 = fmaxf(a3 + bv.w, 0.f);
        uint2 pk;
        pk.x = (uint)f2bf(o0) | ((uint)f2bf(o1) << 16);
        pk.y = (uint)f2bf(o2) | ((uint)f2bf(o3) << 16);
        *(uint2*)&outbf[(size_t)n * HID + COL0 + c4] = pk;
    }
}

// ---------------------------------------------------------------------------
// Fused mean pool + classifier: one block per graph.
// ---------------------------------------------------------------------------
__global__ __launch_bounds__(256) void pool_classify(const ushort* __restrict__ h,
                                                     const int* __restrict__ gstart,
                                                     const float* __restrict__ Wc,
                                                     const float* __restrict__ bc,
                                                     float* __restrict__ out) {
    int g = blockIdx.x;
    int tid = threadIdx.x;
    int d = tid & 127, par = tid >> 7;
    int beg = gstart[g], end = gstart[g + 1];
    float acc = 0.f;
    for (int i = beg + par; i < end; i += 2)
        acc += bfbits2f(((uint)h[(size_t)i * HID + d]) << 16);
    __shared__ float part[256];
    __shared__ float red[2];
    part[tid] = acc;
    __syncthreads();
    float p = 0.f;
    if (par == 0) {
        float s = part[d] + part[128 + d];
        float cntf = fmaxf((float)(end - beg), 1.f);
        p = (s / cntf) * Wc[d];
    }
    for (int o = 32; o; o >>= 1) p += __shfl_xor(p, o, 64);
    if (tid == 0)  red[0] = p;
    if (tid == 64) red[1] = p;
    __syncthreads();
    if (tid == 0)
        out[g] = 1.f / (1.f + expf(-(red[0] + red[1] + bc[0])));
}

// ---------------------------------------------------------------------------
extern "C" void kernel_launch(void* const* d_in, const int* in_sizes, int n_in,
                              void* d_out, int out_size, void* d_ws, size_t ws_size,
                              hipStream_t stream) {
    const float* x     = (const float*)d_in[0];
    const int*   ei    = (const int*)d_in[1];
    const int*   batch = (const int*)d_in[2];
    const float* W1    = (const float*)d_in[3];
    const float* as1   = (const float*)d_in[4];
    const float* ad1   = (const float*)d_in[5];
    const float* b1    = (const float*)d_in[6];
    const float* W2    = (const float*)d_in[7];
    const float* as2   = (const float*)d_in[8];
    const float* ad2   = (const float*)d_in[9];
    const float* b2    = (const float*)d_in[10];
    const float* Wc    = (const float*)d_in[11];
    const float* bc    = (const float*)d_in[12];
    float* out = (float*)d_out;

    char* p = (char*)d_ws;
    auto alloc = [&](size_t bytes) {
        void* r = (void*)p;
        p += (bytes + 255) & ~(size_t)255;
        return r;
    };
    ushort* h0     = (ushort*)alloc((size_t)N_NODES * HID * 2);   // gemm1 out / agg2 out
    ushort* h1     = (ushort*)alloc((size_t)N_NODES * HID * 2);   // agg1 out
    ushort* h2     = (ushort*)alloc((size_t)N_NODES * HID * 2);   // gemm2 out
    float*  alS    = (float*)alloc((size_t)N_NODES * 4);
    float*  alD    = (float*)alloc((size_t)N_NODES * 4);
    uint*   staged = (uint*)alloc((size_t)NBKT * CAPB * 4);       // 4.8 MB
    ushort* csr    = (ushort*)alloc((size_t)E_TOT * 2);           // 1.7 MB
    float*  coefb  = (float*)alloc((size_t)E_TOT * 4);            // 3.4 MB
    int*    rstart = (int*)alloc((size_t)(N_NODES + 1) * 4);
    int*    bbase  = (int*)alloc((NBKT + 1) * 4);
    int*    gcur   = (int*)alloc((NBKT + 1) * 4);
    int*    gstart = (int*)alloc((N_GRAPHS + 1) * 4);
    ushort* Wt1    = (ushort*)alloc((size_t)128 * 256 * 2);
    ushort* Wt2    = (ushort*)alloc((size_t)128 * 128 * 2);

    const int* edge_src = ei;
    const int* edge_dst = ei + N_EDGES;

    // CSR build + weight prep (no memsets, fused dispatches)
    prep<<<192, 256, 0, stream>>>(W1, W2, Wt1, Wt2, gcur);
    bin_scatter<<<NB3, 256, 0, stream>>>(edge_src, edge_dst, gcur, staged);
    scan_bounds<<<NB_BOUNDS + 1, 256, 0, stream>>>(gcur, bbase, rstart, batch, gstart);
    bucket_build<<<NBKT, 256, 0, stream>>>(staged, bbase, rstart, csr);

    // Layer 1
    gemm_mfma<256, false><<<(N_NODES + 63) / 64, 256, 0, stream>>>(
        x, Wt1, h0, as1, ad1, alS, alD, N_NODES);
    gat_agg_half<0, true><<<N_NODES / 4, 256, 0, stream>>>(
        h0, alS, alD, rstart, csr, coefb, b1, h1);
    gat_agg_half<64, false><<<N_NODES / 4, 256, 0, stream>>>(
        h0, alS, alD, rstart, csr, coefb, b1, h1);

    // Layer 2
    gemm_mfma<128, true><<<(N_NODES + 63) / 64, 256, 0, stream>>>(
        h1, Wt2, h2, as2, ad2, alS, alD, N_NODES);
    gat_agg_half<0, true><<<N_NODES / 4, 256, 0, stream>>>(
        h2, alS, alD, rstart, csr, coefb, b2, h0);
    gat_agg_half<64, false><<<N_NODES / 4, 256, 0, stream>>>(
        h2, alS, alD, rstart, csr, coefb, b2, h0);

    // Pool + classify (fused)
    pool_classify<<<N_GRAPHS, 256, 0, stream>>>(h0, gstart, Wc, bc, out);
}

// Round 7
// 283.379 us; speedup vs baseline: 1.3410x; 1.3410x over previous
//
#include <hip/hip_runtime.h>
#include <hip/hip_bf16.h>
#include <math.h>

// Problem constants (from reference)
#define N_NODES 50000
#define N_EDGES 800000
#define E_TOT   (N_EDGES + N_NODES)   // edges + self loops = 850000
#define HID     128
#define N_GRAPHS 64
#define NEG_SLOPE 0.2f

// Radix partition params
#define NBKT 196                      // buckets of 256 dst nodes
#define CAPB 6144                     // fixed bucket capacity (mean 4337, +27 sigma)
#define CHUNK3 4096
#define NB3  ((E_TOT + CHUNK3 - 1) / CHUNK3)    // 208
#define NB_BOUNDS ((N_NODES + 255) / 256)       // 196

typedef __attribute__((ext_vector_type(8))) short bf16x8;
typedef __attribute__((ext_vector_type(4))) float f32x4;
typedef __attribute__((ext_vector_type(2))) float f32x2;

__device__ __forceinline__ ushort f2bf(float f) {
    union { float f; uint u; } x; x.f = f;
    uint r = x.u + 0x7fffu + ((x.u >> 16) & 1u);   // round-to-nearest-even
    return (ushort)(r >> 16);
}
__device__ __forceinline__ float bfbits2f(uint bits_hi) {
    union { uint u; float f; } x; x.u = bits_hi;
    return x.f;
}

// ---------------------------------------------------------------------------
// Prep: convert+transpose both weight matrices, zero gcur. One dispatch.
// ---------------------------------------------------------------------------
__global__ __launch_bounds__(256) void prep(const float* __restrict__ W1,
                                            const float* __restrict__ W2,
                                            ushort* __restrict__ Wt1,
                                            ushort* __restrict__ Wt2,
                                            int* __restrict__ gcur) {
    int idx = blockIdx.x * 256 + threadIdx.x;
    if (idx < 256 * 128) {
        int k = idx >> 7, n = idx & 127;
        Wt1[n * 256 + k] = f2bf(W1[idx]);
    } else if (idx < 256 * 128 + 128 * 128) {
        int j = idx - 256 * 128;
        int k = j >> 7, n = j & 127;
        Wt2[n * 128 + k] = f2bf(W2[j]);
    }
    if (idx <= NBKT) gcur[idx] = 0;
}

// ---------------------------------------------------------------------------
// P3: block-local bucket ordering in LDS, coalesced run writes into
// fixed-capacity bucket slots. val = bucket(8) | src(16) | dst&255 (8).
// ---------------------------------------------------------------------------
__global__ __launch_bounds__(256) void bin_scatter(const int* __restrict__ edge_src,
                                                   const int* __restrict__ edge_dst,
                                                   int* __restrict__ gcur,
                                                   uint* __restrict__ staged) {
    __shared__ int hist[256], scan_s[256], base_l[256], cur[256], runbase[256];
    __shared__ uint vals[CHUNK3];
    int tid = threadIdx.x;
    int e0 = blockIdx.x * CHUNK3;
    int cnt = min(CHUNK3, E_TOT - e0);

    hist[tid] = 0;
    __syncthreads();
    for (int i = tid; i < cnt; i += 256) {
        int e = e0 + i;
        int d = (e < N_EDGES) ? edge_dst[e] : (e - N_EDGES);
        atomicAdd(&hist[d >> 8], 1);
    }
    __syncthreads();
    int v = hist[tid];
    scan_s[tid] = v;
    __syncthreads();
    for (int off = 1; off < 256; off <<= 1) {
        int t = (tid >= off) ? scan_s[tid - off] : 0;
        __syncthreads();
        scan_s[tid] += t;
        __syncthreads();
    }
    base_l[tid] = scan_s[tid] - v;
    cur[tid] = scan_s[tid] - v;
    __syncthreads();
    for (int i = tid; i < cnt; i += 256) {
        int e = e0 + i;
        int s, d;
        if (e < N_EDGES) { s = edge_src[e]; d = edge_dst[e]; }
        else             { s = d = e - N_EDGES; }
        int p = atomicAdd(&cur[d >> 8], 1);
        vals[p] = ((uint)(d >> 8) << 24) | ((uint)s << 8) | (uint)(d & 255);
    }
    __syncthreads();
    if (tid < NBKT && hist[tid] > 0) runbase[tid] = atomicAdd(&gcur[tid], hist[tid]);
    __syncthreads();
    for (int i = tid; i < cnt; i += 256) {
        uint v2 = vals[i];
        int b = (int)(v2 >> 24);
        int idx = runbase[b] + (i - base_l[b]);
        if (idx < CAPB) staged[b * CAPB + idx] = v2;
    }
}

// ---------------------------------------------------------------------------
// Fused: block NB_BOUNDS does the bucket scan; blocks 0..NB_BOUNDS-1 do
// graph boundaries from sorted batch array.
// ---------------------------------------------------------------------------
__global__ __launch_bounds__(256) void scan_bounds(const int* __restrict__ gcur,
                                                   int* __restrict__ bbase,
                                                   int* __restrict__ row_start,
                                                   const int* __restrict__ batch,
                                                   int* __restrict__ gstart) {
    int tid = threadIdx.x;
    if (blockIdx.x == NB_BOUNDS) {
        __shared__ int s[256];
        int v = (tid < NBKT) ? gcur[tid] : 0;
        s[tid] = v;
        __syncthreads();
        for (int off = 1; off < 256; off <<= 1) {
            int t = (tid >= off) ? s[tid - off] : 0;
            __syncthreads();
            s[tid] += t;
            __syncthreads();
        }
        if (tid < NBKT) bbase[tid] = s[tid] - v;
        if (tid == 255) { bbase[NBKT] = s[255]; row_start[N_NODES] = s[255]; }
    } else {
        int i = blockIdx.x * 256 + tid;
        if (i >= N_NODES) return;
        int b  = batch[i];
        int bp = (i == 0) ? -1 : batch[i - 1];
        for (int g = bp + 1; g <= b; g++) gstart[g] = i;
        if (i == N_NODES - 1) {
            for (int g = b + 1; g <= N_GRAPHS; g++) gstart[g] = N_NODES;
        }
    }
}

// ---------------------------------------------------------------------------
// P4: one block per bucket; exact per-node CSR (ushort src) + row_start
// ---------------------------------------------------------------------------
__global__ __launch_bounds__(256) void bucket_build(const uint* __restrict__ staged,
                                                    const int* __restrict__ bbase,
                                                    int* __restrict__ row_start,
                                                    ushort* __restrict__ csr_src) {
    __shared__ int hist[256], scan_s[256], base_l[256];
    __shared__ uint lv[CAPB];
    int tid = threadIdx.x;
    int b = blockIdx.x;
    int base = bbase[b];
    int cnt = bbase[b + 1] - base;

    hist[tid] = 0;
    __syncthreads();
    for (int i = tid; i < cnt; i += 256) {
        uint v = staged[b * CAPB + i];
        lv[i] = v;
        atomicAdd(&hist[v & 255], 1);
    }
    __syncthreads();
    int v0 = hist[tid];
    scan_s[tid] = v0;
    __syncthreads();
    for (int off = 1; off < 256; off <<= 1) {
        int t = (tid >= off) ? scan_s[tid - off] : 0;
        __syncthreads();
        scan_s[tid] += t;
        __syncthreads();
    }
    int excl = scan_s[tid] - v0;
    base_l[tid] = excl;
    int node = b * 256 + tid;
    if (node < N_NODES) row_start[node] = base + excl;
    __syncthreads();
    for (int i = tid; i < cnt; i += 256) {
        uint v = lv[i];
        int pos = base + atomicAdd(&base_l[v & 255], 1);
        csr_src[pos] = (ushort)((v >> 8) & 0xFFFFu);
    }
}

// ---------------------------------------------------------------------------
// BF16 MFMA GEMM + fused alpha epilogue + fp8 e4m3 shadow of C for gathers.
// ---------------------------------------------------------------------------
template <int K, bool ABF>
__global__ __launch_bounds__(256) void gemm_mfma(const void* __restrict__ Aptr,
                                                 const ushort* __restrict__ Wt,
                                                 ushort* __restrict__ Cbf,
                                                 unsigned char* __restrict__ C8,
                                                 const float* __restrict__ a_sv,
                                                 const float* __restrict__ a_dv,
                                                 float* __restrict__ alpha_s,
                                                 float* __restrict__ alpha_d, int M) {
    constexpr int KC = 64;
    constexpr int AP = 72;
    __shared__ ushort As[64 * AP];
    __shared__ ushort Bs[128 * AP];

    int tid = threadIdx.x;
    int lane = tid & 63;
    int wv = tid >> 6;
    int mrow = lane & 15;
    int quad = lane >> 4;
    int row0 = blockIdx.x * 64;

    f32x4 acc[8];
#pragma unroll
    for (int t = 0; t < 8; t++) acc[t] = (f32x4){0.f, 0.f, 0.f, 0.f};

    for (int k0 = 0; k0 < K; k0 += KC) {
        if constexpr (!ABF) {
            const float* A = (const float*)Aptr;
#pragma unroll
            for (int p = 0; p < 2; p++) {
                int c = p * 256 + tid;
                int r = c >> 3;
                int kk = (c & 7) * 8;
                int grow = row0 + r;
                float4 v0 = make_float4(0.f, 0.f, 0.f, 0.f);
                float4 v1 = v0;
                if (grow < M) {
                    const float* src = &A[(size_t)grow * K + k0 + kk];
                    v0 = *(const float4*)src;
                    v1 = *(const float4*)(src + 4);
                }
                uint4 w;
                w.x = (uint)f2bf(v0.x) | ((uint)f2bf(v0.y) << 16);
                w.y = (uint)f2bf(v0.z) | ((uint)f2bf(v0.w) << 16);
                w.z = (uint)f2bf(v1.x) | ((uint)f2bf(v1.y) << 16);
                w.w = (uint)f2bf(v1.z) | ((uint)f2bf(v1.w) << 16);
                *(uint4*)&As[r * AP + kk] = w;
            }
        } else {
            const ushort* A = (const ushort*)Aptr;
#pragma unroll
            for (int p = 0; p < 2; p++) {
                int c = p * 256 + tid;
                int r = c >> 3;
                int kk = (c & 7) * 8;
                int grow = row0 + r;
                uint4 v = make_uint4(0, 0, 0, 0);
                if (grow < M) v = *(const uint4*)&A[(size_t)grow * K + k0 + kk];
                *(uint4*)&As[r * AP + kk] = v;
            }
        }
#pragma unroll
        for (int p = 0; p < 4; p++) {
            int c = p * 256 + tid;
            int n = c >> 3;
            int kk = (c & 7) * 8;
            uint4 v = *(const uint4*)&Wt[(size_t)n * K + k0 + kk];
            *(uint4*)&Bs[n * AP + kk] = v;
        }
        __syncthreads();

        const ushort* arow = &As[(wv * 16 + mrow) * AP + quad * 8];
        const ushort* brow = &Bs[mrow * AP + quad * 8];
#pragma unroll
        for (int ks = 0; ks < KC; ks += 32) {
            bf16x8 a = *(const bf16x8*)&arow[ks];
#pragma unroll
            for (int t = 0; t < 8; t++) {
                bf16x8 b = *(const bf16x8*)&brow[t * 16 * AP + ks];
                acc[t] = __builtin_amdgcn_mfma_f32_16x16x32_bf16(a, b, acc[t], 0, 0, 0);
            }
        }
        __syncthreads();
    }

    // Fused alpha epilogue
    float as_r[8], ad_r[8];
#pragma unroll
    for (int t = 0; t < 8; t++) {
        int col = t * 16 + mrow;
        as_r[t] = a_sv[col];
        ad_r[t] = a_dv[col];
    }
#pragma unroll
    for (int r = 0; r < 4; r++) {
        float ps = 0.f, pd = 0.f;
#pragma unroll
        for (int t = 0; t < 8; t++) {
            ps = fmaf(acc[t][r], as_r[t], ps);
            pd = fmaf(acc[t][r], ad_r[t], pd);
        }
#pragma unroll
        for (int o = 1; o < 16; o <<= 1) {
            ps += __shfl_xor(ps, o, 64);
            pd += __shfl_xor(pd, o, 64);
        }
        int row = row0 + wv * 16 + quad * 4 + r;
        if (mrow == 0 && row < M) {
            alpha_s[row] = ps;
            alpha_d[row] = pd;
        }
    }

    // C write: bf16 + fp8 e4m3 shadow (C/D layout: col=lane&15, row=quad*4+reg)
#pragma unroll
    for (int t = 0; t < 8; t++) {
#pragma unroll
        for (int r = 0; r < 4; r++) {
            int row = row0 + wv * 16 + quad * 4 + r;
            if (row < M) {
                float vv = acc[t][r];
                Cbf[(size_t)row * HID + t * 16 + mrow] = f2bf(vv);
                uint p8 = (uint)__builtin_amdgcn_cvt_pk_fp8_f32(vv, vv, 0, false);
                C8[(size_t)row * HID + t * 16 + mrow] = (unsigned char)(p8 & 0xFF);
            }
        }
    }
}

// ---------------------------------------------------------------------------
// GAT aggregation, fp8 gather: 4 nodes/block, one wave per node (per-wave LDS
// segment, no cross-wave barriers). Single alpha sweep (shift-invariant
// softmax), chunk-0 exp cached in registers. Quarter-wave per edge: 16 lanes
// x uint2 = 128 B = full fp8 row; batch-4 -> 16 loads in flight per wave.
// fp32 accumulate, bf16 output with bias + ReLU.
// ---------------------------------------------------------------------------
__global__ __launch_bounds__(256) void gat_aggregate(const unsigned char* __restrict__ h8,
                                                     const float* __restrict__ alpha_s,
                                                     const float* __restrict__ alpha_d,
                                                     const int* __restrict__ row_start,
                                                     const ushort* __restrict__ csr_src,
                                                     const float* __restrict__ bias,
                                                     ushort* __restrict__ outbf) {
    __shared__ float coefs[4][64];
    __shared__ uint  soffs[4][64];
    int wv = threadIdx.x >> 6;
    int lane = threadIdx.x & 63;
    int n = blockIdx.x * 4 + wv;       // grid = N_NODES/4 exactly
    float* coef = coefs[wv];
    uint*  soff = soffs[wv];

    int beg = row_start[n];
    int deg = row_start[n + 1] - beg;
    float adn = alpha_d[n];

    // Sweep 1: denom; chunk-0 exp/src cached in registers
    float ex0 = 0.f;
    int s0r = 0;
    if (lane < deg) {
        s0r = csr_src[beg + lane];
        float e = alpha_s[s0r] + adn;
        e = (e > 0.f) ? e : e * NEG_SLOPE;
        ex0 = __expf(e);
    }
    float ssum = ex0;
    for (int k = 64 + lane; k < deg; k += 64) {
        int s = csr_src[beg + k];
        float e = alpha_s[s] + adn;
        e = (e > 0.f) ? e : e * NEG_SLOPE;
        ssum += __expf(e);
    }
    for (int o = 32; o; o >>= 1) ssum += __shfl_xor(ssum, o, 64);
    float inv = 1.f / ssum;

    int q = lane >> 4;             // edge slot 0..3
    int c8 = (lane & 15) * 8;      // 8 columns owned by this lane
    float a[8];
#pragma unroll
    for (int i = 0; i < 8; i++) a[i] = 0.f;
    const char* hbase = (const char*)h8 + c8;

    for (int c0 = 0; c0 < deg; c0 += 64) {
        int k = c0 + lane;
        if (k < deg) {
            if (c0 == 0) {
                coef[lane] = ex0 * inv;
                soff[lane] = (uint)s0r * HID;
            } else {
                int s = csr_src[beg + k];
                float e = alpha_s[s] + adn;
                e = (e > 0.f) ? e : e * NEG_SLOPE;
                coef[lane] = __expf(e) * inv;
                soff[lane] = (uint)s * HID;
            }
        }
        __builtin_amdgcn_wave_barrier();
        int cnt = min(64, deg - c0);
        int T = (cnt - q + 3) >> 2;    // edges j = 4t+q < cnt
        int t = 0;
        for (; t + 4 <= T; t += 4) {
            float w[4]; uint off[4]; uint2 v[4];
#pragma unroll
            for (int b = 0; b < 4; b++) {
                int j = 4 * (t + b) + q;
                w[b] = coef[j];
                off[b] = soff[j];
            }
#pragma unroll
            for (int b = 0; b < 4; b++)
                v[b] = *(const uint2*)(hbase + off[b]);
#pragma unroll
            for (int b = 0; b < 4; b++) {
                f32x2 p0 = __builtin_amdgcn_cvt_pk_f32_fp8((int)v[b].x, false);
                f32x2 p1 = __builtin_amdgcn_cvt_pk_f32_fp8((int)v[b].x, true);
                f32x2 p2 = __builtin_amdgcn_cvt_pk_f32_fp8((int)v[b].y, false);
                f32x2 p3 = __builtin_amdgcn_cvt_pk_f32_fp8((int)v[b].y, true);
                a[0] = fmaf(w[b], p0.x, a[0]); a[1] = fmaf(w[b], p0.y, a[1]);
                a[2] = fmaf(w[b], p1.x, a[2]); a[3] = fmaf(w[b], p1.y, a[3]);
                a[4] = fmaf(w[b], p2.x, a[4]); a[5] = fmaf(w[b], p2.y, a[5]);
                a[6] = fmaf(w[b], p3.x, a[6]); a[7] = fmaf(w[b], p3.y, a[7]);
            }
        }
        for (; t < T; t++) {
            int j = 4 * t + q;
            float w = coef[j];
            uint2 v = *(const uint2*)(hbase + soff[j]);
            f32x2 p0 = __builtin_amdgcn_cvt_pk_f32_fp8((int)v.x, false);
            f32x2 p1 = __builtin_amdgcn_cvt_pk_f32_fp8((int)v.x, true);
            f32x2 p2 = __builtin_amdgcn_cvt_pk_f32_fp8((int)v.y, false);
            f32x2 p3 = __builtin_amdgcn_cvt_pk_f32_fp8((int)v.y, true);
            a[0] = fmaf(w, p0.x, a[0]); a[1] = fmaf(w, p0.y, a[1]);
            a[2] = fmaf(w, p1.x, a[2]); a[3] = fmaf(w, p1.y, a[3]);
            a[4] = fmaf(w, p2.x, a[4]); a[5] = fmaf(w, p2.y, a[5]);
            a[6] = fmaf(w, p3.x, a[6]); a[7] = fmaf(w, p3.y, a[7]);
        }
        __builtin_amdgcn_wave_barrier();
    }

    // Merge quarters, bias + ReLU, bf16 write (16 lanes x 16B per node)
#pragma unroll
    for (int i = 0; i < 8; i++) {
        a[i] += __shfl_xor(a[i], 16, 64);
        a[i] += __shfl_xor(a[i], 32, 64);
    }
    if (q == 0) {
        float4 b0 = *(const float4*)&bias[c8];
        float4 b1 = *(const float4*)&bias[c8 + 4];
        float o0 = fmaxf(a[0] + b0.x, 0.f), o1 = fmaxf(a[1] + b0.y, 0.f);
        float o2 = fmaxf(a[2] + b0.z, 0.f), o3 = fmaxf(a[3] + b0.w, 0.f);
        float o4 = fmaxf(a[4] + b1.x, 0.f), o5 = fmaxf(a[5] + b1.y, 0.f);
        float o6 = fmaxf(a[6] + b1.z, 0.f), o7 = fmaxf(a[7] + b1.w, 0.f);
        uint4 pk;
        pk.x = (uint)f2bf(o0) | ((uint)f2bf(o1) << 16);
        pk.y = (uint)f2bf(o2) | ((uint)f2bf(o3) << 16);
        pk.z = (uint)f2bf(o4) | ((uint)f2bf(o5) << 16);
        pk.w = (uint)f2bf(o6) | ((uint)f2bf(o7) << 16);
        *(uint4*)&outbf[(size_t)n * HID + c8] = pk;
    }
}

// ---------------------------------------------------------------------------
// Mean pool per graph (two-stage, bf16 input) + classifier
// ---------------------------------------------------------------------------
__global__ __launch_bounds__(128) void pool_partial(const ushort* __restrict__ h,
                                                    const int* __restrict__ gstart,
                                                    float* __restrict__ pool) {
    int g = blockIdx.x;
    int slice = blockIdx.y;
    int d = threadIdx.x;
    int beg = gstart[g], end = gstart[g + 1];
    float acc = 0.f;
    for (int i = beg + slice; i < end; i += 16)
        acc += bfbits2f(((uint)h[(size_t)i * HID + d]) << 16);
    atomicAdd(&pool[g * HID + d], acc);
}

__global__ __launch_bounds__(128) void classify(const float* __restrict__ pool,
                                                const int* __restrict__ gstart,
                                                const float* __restrict__ Wc,
                                                const float* __restrict__ bc,
                                                float* __restrict__ out) {
    int g = blockIdx.x;
    int d = threadIdx.x;
    float cnt = (float)(gstart[g + 1] - gstart[g]);
    float pooled = pool[g * HID + d] / fmaxf(cnt, 1.f);
    float p = pooled * Wc[d];
    __shared__ float red[2];
    for (int o = 32; o; o >>= 1) p += __shfl_xor(p, o, 64);
    if ((d & 63) == 0) red[d >> 6] = p;
    __syncthreads();
    if (d == 0) {
        float t = red[0] + red[1] + bc[0];
        out[g] = 1.f / (1.f + expf(-t));
    }
}

// ---------------------------------------------------------------------------
extern "C" void kernel_launch(void* const* d_in, const int* in_sizes, int n_in,
                              void* d_out, int out_size, void* d_ws, size_t ws_size,
                              hipStream_t stream) {
    const float* x     = (const float*)d_in[0];
    const int*   ei    = (const int*)d_in[1];
    const int*   batch = (const int*)d_in[2];
    const float* W1    = (const float*)d_in[3];
    const float* as1   = (const float*)d_in[4];
    const float* ad1   = (const float*)d_in[5];
    const float* b1    = (const float*)d_in[6];
    const float* W2    = (const float*)d_in[7];
    const float* as2   = (const float*)d_in[8];
    const float* ad2   = (const float*)d_in[9];
    const float* b2    = (const float*)d_in[10];
    const float* Wc    = (const float*)d_in[11];
    const float* bc    = (const float*)d_in[12];
    float* out = (float*)d_out;

    char* p = (char*)d_ws;
    auto alloc = [&](size_t bytes) {
        void* r = (void*)p;
        p += (bytes + 255) & ~(size_t)255;
        return r;
    };
    ushort* h0     = (ushort*)alloc((size_t)N_NODES * HID * 2);   // gemm1 out / agg2 out
    ushort* h1     = (ushort*)alloc((size_t)N_NODES * HID * 2);   // agg1 out
    ushort* h2     = (ushort*)alloc((size_t)N_NODES * HID * 2);   // gemm2 out
    unsigned char* h8 = (unsigned char*)alloc((size_t)N_NODES * HID); // fp8 shadow (gemm out)
    float*  alS    = (float*)alloc((size_t)N_NODES * 4);
    float*  alD    = (float*)alloc((size_t)N_NODES * 4);
    uint*   staged = (uint*)alloc((size_t)NBKT * CAPB * 4);       // 4.8 MB
    ushort* csr    = (ushort*)alloc((size_t)E_TOT * 2);           // 1.7 MB
    int*    rstart = (int*)alloc((size_t)(N_NODES + 1) * 4);
    int*    bbase  = (int*)alloc((NBKT + 1) * 4);
    int*    gcur   = (int*)alloc((NBKT + 1) * 4);
    int*    gstart = (int*)alloc((N_GRAPHS + 1) * 4);
    float*  pool   = (float*)alloc(N_GRAPHS * HID * 4);
    ushort* Wt1    = (ushort*)alloc((size_t)128 * 256 * 2);
    ushort* Wt2    = (ushort*)alloc((size_t)128 * 128 * 2);

    const int* edge_src = ei;
    const int* edge_dst = ei + N_EDGES;

    hipMemsetAsync(pool, 0, (size_t)N_GRAPHS * HID * 4, stream);

    // CSR build + weight prep
    prep<<<192, 256, 0, stream>>>(W1, W2, Wt1, Wt2, gcur);
    bin_scatter<<<NB3, 256, 0, stream>>>(edge_src, edge_dst, gcur, staged);
    scan_bounds<<<NB_BOUNDS + 1, 256, 0, stream>>>(gcur, bbase, rstart, batch, gstart);
    bucket_build<<<NBKT, 256, 0, stream>>>(staged, bbase, rstart, csr);

    // Layer 1
    gemm_mfma<256, false><<<(N_NODES + 63) / 64, 256, 0, stream>>>(
        x, Wt1, h0, h8, as1, ad1, alS, alD, N_NODES);
    gat_aggregate<<<N_NODES / 4, 256, 0, stream>>>(h8, alS, alD, rstart, csr, b1, h1);

    // Layer 2
    gemm_mfma<128, true><<<(N_NODES + 63) / 64, 256, 0, stream>>>(
        h1, Wt2, h2, h8, as2, ad2, alS, alD, N_NODES);
    gat_aggregate<<<N_NODES / 4, 256, 0, stream>>>(h8, alS, alD, rstart, csr, b2, h0);

    // Pool + classify
    pool_partial<<<dim3(N_GRAPHS, 16), HID, 0, stream>>>(h0, gstart, pool);
    classify<<<N_GRAPHS, HID, 0, stream>>>(pool, gstart, Wc, bc, out);
}

// Round 8
// 239.241 us; speedup vs baseline: 1.5884x; 1.1845x over previous
//
#include <hip/hip_runtime.h>
#include <hip/hip_bf16.h>
#include <math.h>

// Problem constants (from reference)
#define N_NODES 50000
#define N_EDGES 800000
#define E_TOT   (N_EDGES + N_NODES)   // edges + self loops = 850000
#define HID     128
#define N_GRAPHS 64
#define NEG_SLOPE 0.2f

// Radix partition params
#define NBKT 196                      // buckets of 256 dst nodes
#define CAPB 6144                     // fixed bucket capacity (mean 4337, +27 sigma)
#define CHUNK3 4096
#define NB3  ((E_TOT + CHUNK3 - 1) / CHUNK3)    // 208
#define NB_BOUNDS ((N_NODES + 255) / 256)       // 196

typedef __attribute__((ext_vector_type(8))) short bf16x8;
typedef __attribute__((ext_vector_type(4))) float f32x4;

__device__ __forceinline__ ushort f2bf(float f) {
    union { float f; uint u; } x; x.f = f;
    uint r = x.u + 0x7fffu + ((x.u >> 16) & 1u);   // round-to-nearest-even
    return (ushort)(r >> 16);
}
__device__ __forceinline__ float bfbits2f(uint bits_hi) {
    union { uint u; float f; } x; x.u = bits_hi;
    return x.f;
}

// ---------------------------------------------------------------------------
// Prep: convert+transpose both weight matrices, zero gcur. One dispatch.
// ---------------------------------------------------------------------------
__global__ __launch_bounds__(256) void prep(const float* __restrict__ W1,
                                            const float* __restrict__ W2,
                                            ushort* __restrict__ Wt1,
                                            ushort* __restrict__ Wt2,
                                            int* __restrict__ gcur) {
    int idx = blockIdx.x * 256 + threadIdx.x;
    if (idx < 256 * 128) {
        int k = idx >> 7, n = idx & 127;
        Wt1[n * 256 + k] = f2bf(W1[idx]);
    } else if (idx < 256 * 128 + 128 * 128) {
        int j = idx - 256 * 128;
        int k = j >> 7, n = j & 127;
        Wt2[n * 128 + k] = f2bf(W2[j]);
    }
    if (idx <= NBKT) gcur[idx] = 0;
}

// ---------------------------------------------------------------------------
// P3: block-local bucket ordering in LDS, coalesced run writes into
// fixed-capacity bucket slots. val = bucket(8) | src(16) | dst&255 (8).
// ---------------------------------------------------------------------------
__global__ __launch_bounds__(256) void bin_scatter(const int* __restrict__ edge_src,
                                                   const int* __restrict__ edge_dst,
                                                   int* __restrict__ gcur,
                                                   uint* __restrict__ staged) {
    __shared__ int hist[256], scan_s[256], base_l[256], cur[256], runbase[256];
    __shared__ uint vals[CHUNK3];
    int tid = threadIdx.x;
    int e0 = blockIdx.x * CHUNK3;
    int cnt = min(CHUNK3, E_TOT - e0);

    hist[tid] = 0;
    __syncthreads();
    for (int i = tid; i < cnt; i += 256) {
        int e = e0 + i;
        int d = (e < N_EDGES) ? edge_dst[e] : (e - N_EDGES);
        atomicAdd(&hist[d >> 8], 1);
    }
    __syncthreads();
    int v = hist[tid];
    scan_s[tid] = v;
    __syncthreads();
    for (int off = 1; off < 256; off <<= 1) {
        int t = (tid >= off) ? scan_s[tid - off] : 0;
        __syncthreads();
        scan_s[tid] += t;
        __syncthreads();
    }
    base_l[tid] = scan_s[tid] - v;
    cur[tid] = scan_s[tid] - v;
    __syncthreads();
    for (int i = tid; i < cnt; i += 256) {
        int e = e0 + i;
        int s, d;
        if (e < N_EDGES) { s = edge_src[e]; d = edge_dst[e]; }
        else             { s = d = e - N_EDGES; }
        int p = atomicAdd(&cur[d >> 8], 1);
        vals[p] = ((uint)(d >> 8) << 24) | ((uint)s << 8) | (uint)(d & 255);
    }
    __syncthreads();
    if (tid < NBKT && hist[tid] > 0) runbase[tid] = atomicAdd(&gcur[tid], hist[tid]);
    __syncthreads();
    for (int i = tid; i < cnt; i += 256) {
        uint v2 = vals[i];
        int b = (int)(v2 >> 24);
        int idx = runbase[b] + (i - base_l[b]);
        if (idx < CAPB) staged[b * CAPB + idx] = v2;
    }
}

// ---------------------------------------------------------------------------
// Fused: block NB_BOUNDS does the bucket scan; blocks 0..NB_BOUNDS-1 do
// graph boundaries from sorted batch array.
// ---------------------------------------------------------------------------
__global__ __launch_bounds__(256) void scan_bounds(const int* __restrict__ gcur,
                                                   int* __restrict__ bbase,
                                                   int* __restrict__ row_start,
                                                   const int* __restrict__ batch,
                                                   int* __restrict__ gstart) {
    int tid = threadIdx.x;
    if (blockIdx.x == NB_BOUNDS) {
        __shared__ int s[256];
        int v = (tid < NBKT) ? gcur[tid] : 0;
        s[tid] = v;
        __syncthreads();
        for (int off = 1; off < 256; off <<= 1) {
            int t = (tid >= off) ? s[tid - off] : 0;
            __syncthreads();
            s[tid] += t;
            __syncthreads();
        }
        if (tid < NBKT) bbase[tid] = s[tid] - v;
        if (tid == 255) { bbase[NBKT] = s[255]; row_start[N_NODES] = s[255]; }
    } else {
        int i = blockIdx.x * 256 + tid;
        if (i >= N_NODES) return;
        int b  = batch[i];
        int bp = (i == 0) ? -1 : batch[i - 1];
        for (int g = bp + 1; g <= b; g++) gstart[g] = i;
        if (i == N_NODES - 1) {
            for (int g = b + 1; g <= N_GRAPHS; g++) gstart[g] = N_NODES;
        }
    }
}

// ---------------------------------------------------------------------------
// P4: one block per bucket; exact per-node CSR (ushort src) + row_start
// ---------------------------------------------------------------------------
__global__ __launch_bounds__(256) void bucket_build(const uint* __restrict__ staged,
                                                    const int* __restrict__ bbase,
                                                    int* __restrict__ row_start,
                                                    ushort* __restrict__ csr_src) {
    __shared__ int hist[256], scan_s[256], base_l[256];
    __shared__ uint lv[CAPB];
    int tid = threadIdx.x;
    int b = blockIdx.x;
    int base = bbase[b];
    int cnt = bbase[b + 1] - base;

    hist[tid] = 0;
    __syncthreads();
    for (int i = tid; i < cnt; i += 256) {
        uint v = staged[b * CAPB + i];
        lv[i] = v;
        atomicAdd(&hist[v & 255], 1);
    }
    __syncthreads();
    int v0 = hist[tid];
    scan_s[tid] = v0;
    __syncthreads();
    for (int off = 1; off < 256; off <<= 1) {
        int t = (tid >= off) ? scan_s[tid - off] : 0;
        __syncthreads();
        scan_s[tid] += t;
        __syncthreads();
    }
    int excl = scan_s[tid] - v0;
    base_l[tid] = excl;
    int node = b * 256 + tid;
    if (node < N_NODES) row_start[node] = base + excl;
    __syncthreads();
    for (int i = tid; i < cnt; i += 256) {
        uint v = lv[i];
        int pos = base + atomicAdd(&base_l[v & 255], 1);
        csr_src[pos] = (ushort)((v >> 8) & 0xFFFFu);
    }
}

// ---------------------------------------------------------------------------
// BF16 MFMA GEMM + fused alpha epilogue.
// ---------------------------------------------------------------------------
template <int K, bool ABF>
__global__ __launch_bounds__(256) void gemm_mfma(const void* __restrict__ Aptr,
                                                 const ushort* __restrict__ Wt,
                                                 ushort* __restrict__ Cbf,
                                                 const float* __restrict__ a_sv,
                                                 const float* __restrict__ a_dv,
                                                 float* __restrict__ alpha_s,
                                                 float* __restrict__ alpha_d, int M) {
    constexpr int KC = 64;
    constexpr int AP = 72;
    __shared__ ushort As[64 * AP];
    __shared__ ushort Bs[128 * AP];

    int tid = threadIdx.x;
    int lane = tid & 63;
    int wv = tid >> 6;
    int mrow = lane & 15;
    int quad = lane >> 4;
    int row0 = blockIdx.x * 64;

    f32x4 acc[8];
#pragma unroll
    for (int t = 0; t < 8; t++) acc[t] = (f32x4){0.f, 0.f, 0.f, 0.f};

    for (int k0 = 0; k0 < K; k0 += KC) {
        if constexpr (!ABF) {
            const float* A = (const float*)Aptr;
#pragma unroll
            for (int p = 0; p < 2; p++) {
                int c = p * 256 + tid;
                int r = c >> 3;
                int kk = (c & 7) * 8;
                int grow = row0 + r;
                float4 v0 = make_float4(0.f, 0.f, 0.f, 0.f);
                float4 v1 = v0;
                if (grow < M) {
                    const float* src = &A[(size_t)grow * K + k0 + kk];
                    v0 = *(const float4*)src;
                    v1 = *(const float4*)(src + 4);
                }
                uint4 w;
                w.x = (uint)f2bf(v0.x) | ((uint)f2bf(v0.y) << 16);
                w.y = (uint)f2bf(v0.z) | ((uint)f2bf(v0.w) << 16);
                w.z = (uint)f2bf(v1.x) | ((uint)f2bf(v1.y) << 16);
                w.w = (uint)f2bf(v1.z) | ((uint)f2bf(v1.w) << 16);
                *(uint4*)&As[r * AP + kk] = w;
            }
        } else {
            const ushort* A = (const ushort*)Aptr;
#pragma unroll
            for (int p = 0; p < 2; p++) {
                int c = p * 256 + tid;
                int r = c >> 3;
                int kk = (c & 7) * 8;
                int grow = row0 + r;
                uint4 v = make_uint4(0, 0, 0, 0);
                if (grow < M) v = *(const uint4*)&A[(size_t)grow * K + k0 + kk];
                *(uint4*)&As[r * AP + kk] = v;
            }
        }
#pragma unroll
        for (int p = 0; p < 4; p++) {
            int c = p * 256 + tid;
            int n = c >> 3;
            int kk = (c & 7) * 8;
            uint4 v = *(const uint4*)&Wt[(size_t)n * K + k0 + kk];
            *(uint4*)&Bs[n * AP + kk] = v;
        }
        __syncthreads();

        const ushort* arow = &As[(wv * 16 + mrow) * AP + quad * 8];
        const ushort* brow = &Bs[mrow * AP + quad * 8];
#pragma unroll
        for (int ks = 0; ks < KC; ks += 32) {
            bf16x8 a = *(const bf16x8*)&arow[ks];
#pragma unroll
            for (int t = 0; t < 8; t++) {
                bf16x8 b = *(const bf16x8*)&brow[t * 16 * AP + ks];
                acc[t] = __builtin_amdgcn_mfma_f32_16x16x32_bf16(a, b, acc[t], 0, 0, 0);
            }
        }
        __syncthreads();
    }

    // Fused alpha epilogue
    float as_r[8], ad_r[8];
#pragma unroll
    for (int t = 0; t < 8; t++) {
        int col = t * 16 + mrow;
        as_r[t] = a_sv[col];
        ad_r[t] = a_dv[col];
    }
#pragma unroll
    for (int r = 0; r < 4; r++) {
        float ps = 0.f, pd = 0.f;
#pragma unroll
        for (int t = 0; t < 8; t++) {
            ps = fmaf(acc[t][r], as_r[t], ps);
            pd = fmaf(acc[t][r], ad_r[t], pd);
        }
#pragma unroll
        for (int o = 1; o < 16; o <<= 1) {
            ps += __shfl_xor(ps, o, 64);
            pd += __shfl_xor(pd, o, 64);
        }
        int row = row0 + wv * 16 + quad * 4 + r;
        if (mrow == 0 && row < M) {
            alpha_s[row] = ps;
            alpha_d[row] = pd;
        }
    }

    // C write (C/D layout: col=lane&15, row=quad*4+reg)
#pragma unroll
    for (int t = 0; t < 8; t++) {
#pragma unroll
        for (int r = 0; r < 4; r++) {
            int row = row0 + wv * 16 + quad * 4 + r;
            if (row < M)
                Cbf[(size_t)row * HID + t * 16 + mrow] = f2bf(acc[t][r]);
        }
    }
}

// ---------------------------------------------------------------------------
// GAT aggregation v3: one node per 16-lane quarter (16 nodes/block).
// Unnormalized accumulation (acc = sum exp(e)*h[src], divide at end) removes
// the denominator dependency from the gather. Each lane owns 8 bf16 cols ->
// one uint4 load = full 256B row per quarter; batch-8 -> 8 KB outstanding
// per wave (32 rows in flight). LDS ex/soff padded to 72 (ex=0) so the
// batch loop is branch-free; trip count wave-uniform via shfl-max.
// ---------------------------------------------------------------------------
__global__ __launch_bounds__(256) void gat_aggregate(const ushort* __restrict__ hbf,
                                                     const float* __restrict__ alpha_s,
                                                     const float* __restrict__ alpha_d,
                                                     const int* __restrict__ row_start,
                                                     const ushort* __restrict__ csr_src,
                                                     const float* __restrict__ bias,
                                                     ushort* __restrict__ outbf) {
    __shared__ float exv[4][4][72];
    __shared__ uint  sov[4][4][72];
    int wv = threadIdx.x >> 6;
    int lane = threadIdx.x & 63;
    int q = lane >> 4;             // quarter = node slot
    int l = lane & 15;             // lane within quarter
    int n = blockIdx.x * 16 + wv * 4 + q;   // grid = N_NODES/16 exactly
    float* exq = exv[wv][q];
    uint*  soq = sov[wv][q];

    int beg = row_start[n];
    int deg = row_start[n + 1] - beg;
    float adn = alpha_d[n];
    int c8 = l * 8;
    const char* hbase = (const char*)hbf + c8 * 2;

    float a[8];
#pragma unroll
    for (int i = 0; i < 8; i++) a[i] = 0.f;
    float ssum = 0.f;

    for (int c0 = 0; c0 < deg; c0 += 64) {
        int cnt = min(64, deg - c0);
        // Fill ex/soff for this chunk (pad to 72 with ex=0, soff=0)
        for (int k = l; k < 72; k += 16) {
            if (k < cnt) {
                int s = csr_src[beg + c0 + k];
                float e = alpha_s[s] + adn;
                e = (e > 0.f) ? e : e * NEG_SLOPE;
                float ex = __expf(e);
                exq[k] = ex;
                soq[k] = (uint)s * (HID * 2);
                ssum += ex;
            } else {
                exq[k] = 0.f;
                soq[k] = 0u;
            }
        }
        __builtin_amdgcn_wave_barrier();
        int cm = cnt;
        cm = max(cm, __shfl_xor(cm, 16, 64));
        cm = max(cm, __shfl_xor(cm, 32, 64));
        for (int t0 = 0; t0 < cm; t0 += 8) {
            uint off[8]; uint4 v[8]; float w[8];
#pragma unroll
            for (int b = 0; b < 8; b++) off[b] = soq[t0 + b];
#pragma unroll
            for (int b = 0; b < 8; b++) v[b] = *(const uint4*)(hbase + off[b]);
#pragma unroll
            for (int b = 0; b < 8; b++) w[b] = exq[t0 + b];
#pragma unroll
            for (int b = 0; b < 8; b++) {
                a[0] = fmaf(w[b], bfbits2f(v[b].x << 16), a[0]);
                a[1] = fmaf(w[b], bfbits2f(v[b].x & 0xffff0000u), a[1]);
                a[2] = fmaf(w[b], bfbits2f(v[b].y << 16), a[2]);
                a[3] = fmaf(w[b], bfbits2f(v[b].y & 0xffff0000u), a[3]);
                a[4] = fmaf(w[b], bfbits2f(v[b].z << 16), a[4]);
                a[5] = fmaf(w[b], bfbits2f(v[b].z & 0xffff0000u), a[5]);
                a[6] = fmaf(w[b], bfbits2f(v[b].w << 16), a[6]);
                a[7] = fmaf(w[b], bfbits2f(v[b].w & 0xffff0000u), a[7]);
            }
        }
        __builtin_amdgcn_wave_barrier();
    }

    // Reduce denom within quarter, normalize, bias + ReLU, bf16 write
    ssum += __shfl_xor(ssum, 1, 64);
    ssum += __shfl_xor(ssum, 2, 64);
    ssum += __shfl_xor(ssum, 4, 64);
    ssum += __shfl_xor(ssum, 8, 64);
    float inv = 1.f / ssum;
    float4 b0 = *(const float4*)&bias[c8];
    float4 b1 = *(const float4*)&bias[c8 + 4];
    float o0 = fmaxf(fmaf(a[0], inv, b0.x), 0.f);
    float o1 = fmaxf(fmaf(a[1], inv, b0.y), 0.f);
    float o2 = fmaxf(fmaf(a[2], inv, b0.z), 0.f);
    float o3 = fmaxf(fmaf(a[3], inv, b0.w), 0.f);
    float o4 = fmaxf(fmaf(a[4], inv, b1.x), 0.f);
    float o5 = fmaxf(fmaf(a[5], inv, b1.y), 0.f);
    float o6 = fmaxf(fmaf(a[6], inv, b1.z), 0.f);
    float o7 = fmaxf(fmaf(a[7], inv, b1.w), 0.f);
    uint4 pk;
    pk.x = (uint)f2bf(o0) | ((uint)f2bf(o1) << 16);
    pk.y = (uint)f2bf(o2) | ((uint)f2bf(o3) << 16);
    pk.z = (uint)f2bf(o4) | ((uint)f2bf(o5) << 16);
    pk.w = (uint)f2bf(o6) | ((uint)f2bf(o7) << 16);
    *(uint4*)&outbf[(size_t)n * HID + c8] = pk;
}

// ---------------------------------------------------------------------------
// Mean pool per graph (two-stage, bf16 input) + classifier
// ---------------------------------------------------------------------------
__global__ __launch_bounds__(128) void pool_partial(const ushort* __restrict__ h,
                                                    const int* __restrict__ gstart,
                                                    float* __restrict__ pool) {
    int g = blockIdx.x;
    int slice = blockIdx.y;
    int d = threadIdx.x;
    int beg = gstart[g], end = gstart[g + 1];
    float acc = 0.f;
    for (int i = beg + slice; i < end; i += 16)
        acc += bfbits2f(((uint)h[(size_t)i * HID + d]) << 16);
    atomicAdd(&pool[g * HID + d], acc);
}

__global__ __launch_bounds__(128) void classify(const float* __restrict__ pool,
                                                const int* __restrict__ gstart,
                                                const float* __restrict__ Wc,
                                                const float* __restrict__ bc,
                                                float* __restrict__ out) {
    int g = blockIdx.x;
    int d = threadIdx.x;
    float cnt = (float)(gstart[g + 1] - gstart[g]);
    float pooled = pool[g * HID + d] / fmaxf(cnt, 1.f);
    float p = pooled * Wc[d];
    __shared__ float red[2];
    for (int o = 32; o; o >>= 1) p += __shfl_xor(p, o, 64);
    if ((d & 63) == 0) red[d >> 6] = p;
    __syncthreads();
    if (d == 0) {
        float t = red[0] + red[1] + bc[0];
        out[g] = 1.f / (1.f + expf(-t));
    }
}

// ---------------------------------------------------------------------------
extern "C" void kernel_launch(void* const* d_in, const int* in_sizes, int n_in,
                              void* d_out, int out_size, void* d_ws, size_t ws_size,
                              hipStream_t stream) {
    const float* x     = (const float*)d_in[0];
    const int*   ei    = (const int*)d_in[1];
    const int*   batch = (const int*)d_in[2];
    const float* W1    = (const float*)d_in[3];
    const float* as1   = (const float*)d_in[4];
    const float* ad1   = (const float*)d_in[5];
    const float* b1    = (const float*)d_in[6];
    const float* W2    = (const float*)d_in[7];
    const float* as2   = (const float*)d_in[8];
    const float* ad2   = (const float*)d_in[9];
    const float* b2    = (const float*)d_in[10];
    const float* Wc    = (const float*)d_in[11];
    const float* bc    = (const float*)d_in[12];
    float* out = (float*)d_out;

    char* p = (char*)d_ws;
    auto alloc = [&](size_t bytes) {
        void* r = (void*)p;
        p += (bytes + 255) & ~(size_t)255;
        return r;
    };
    ushort* h0     = (ushort*)alloc((size_t)N_NODES * HID * 2);   // gemm1 out / agg2 out
    ushort* h1     = (ushort*)alloc((size_t)N_NODES * HID * 2);   // agg1 out
    ushort* h2     = (ushort*)alloc((size_t)N_NODES * HID * 2);   // gemm2 out
    float*  alS    = (float*)alloc((size_t)N_NODES * 4);
    float*  alD    = (float*)alloc((size_t)N_NODES * 4);
    uint*   staged = (uint*)alloc((size_t)NBKT * CAPB * 4);       // 4.8 MB
    ushort* csr    = (ushort*)alloc((size_t)E_TOT * 2);           // 1.7 MB
    int*    rstart = (int*)alloc((size_t)(N_NODES + 1) * 4);
    int*    bbase  = (int*)alloc((NBKT + 1) * 4);
    int*    gcur   = (int*)alloc((NBKT + 1) * 4);
    int*    gstart = (int*)alloc((N_GRAPHS + 1) * 4);
    float*  pool   = (float*)alloc(N_GRAPHS * HID * 4);
    ushort* Wt1    = (ushort*)alloc((size_t)128 * 256 * 2);
    ushort* Wt2    = (ushort*)alloc((size_t)128 * 128 * 2);

    const int* edge_src = ei;
    const int* edge_dst = ei + N_EDGES;

    hipMemsetAsync(pool, 0, (size_t)N_GRAPHS * HID * 4, stream);

    // CSR build + weight prep
    prep<<<192, 256, 0, stream>>>(W1, W2, Wt1, Wt2, gcur);
    bin_scatter<<<NB3, 256, 0, stream>>>(edge_src, edge_dst, gcur, staged);
    scan_bounds<<<NB_BOUNDS + 1, 256, 0, stream>>>(gcur, bbase, rstart, batch, gstart);
    bucket_build<<<NBKT, 256, 0, stream>>>(staged, bbase, rstart, csr);

    // Layer 1
    gemm_mfma<256, false><<<(N_NODES + 63) / 64, 256, 0, stream>>>(
        x, Wt1, h0, as1, ad1, alS, alD, N_NODES);
    gat_aggregate<<<N_NODES / 16, 256, 0, stream>>>(h0, alS, alD, rstart, csr, b1, h1);

    // Layer 2
    gemm_mfma<128, true><<<(N_NODES + 63) / 64, 256, 0, stream>>>(
        h1, Wt2, h2, as2, ad2, alS, alD, N_NODES);
    gat_aggregate<<<N_NODES / 16, 256, 0, stream>>>(h2, alS, alD, rstart, csr, b2, h0);

    // Pool + classify
    pool_partial<<<dim3(N_GRAPHS, 16), HID, 0, stream>>>(h0, gstart, pool);
    classify<<<N_GRAPHS, HID, 0, stream>>>(pool, gstart, Wc, bc, out);
}

// Round 9
// 222.655 us; speedup vs baseline: 1.7067x; 1.0745x over previous
//
#include <hip/hip_runtime.h>
#include <hip/hip_bf16.h>
#include <math.h>

// Problem constants (from reference)
#define N_NODES 50000
#define N_EDGES 800000
#define E_TOT   (N_EDGES + N_NODES)   // edges + self loops = 850000
#define HID     128
#define N_GRAPHS 64
#define NEG_SLOPE 0.2f

// Radix partition params
#define NBKT 196                      // buckets of 256 dst nodes
#define CAPB 6144                     // fixed bucket capacity (mean 4337, +27 sigma)
#define CHUNK3 4096
#define NB3  ((E_TOT + CHUNK3 - 1) / CHUNK3)    // 208
#define NBG1 ((N_NODES + 63) / 64)              // 782 gemm blocks (layer 1)
#define NB_BOUNDS ((N_NODES + 255) / 256)       // 196

typedef __attribute__((ext_vector_type(8))) short bf16x8;
typedef __attribute__((ext_vector_type(4))) float f32x4;

__device__ __forceinline__ ushort f2bf(float f) {
    union { float f; uint u; } x; x.f = f;
    uint r = x.u + 0x7fffu + ((x.u >> 16) & 1u);   // round-to-nearest-even
    return (ushort)(r >> 16);
}
__device__ __forceinline__ float bfbits2f(uint bits_hi) {
    union { uint u; float f; } x; x.u = bits_hi;
    return x.f;
}

// ---------------------------------------------------------------------------
// Prep: weight convert+transpose, gcur zero, graph bounds, row_start[N]=E_TOT.
// Blocks 0..191: weights; blocks 192..387: graph bounds.
// ---------------------------------------------------------------------------
__global__ __launch_bounds__(256) void prep(const float* __restrict__ W1,
                                            const float* __restrict__ W2,
                                            ushort* __restrict__ Wt1,
                                            ushort* __restrict__ Wt2,
                                            int* __restrict__ gcur,
                                            const int* __restrict__ batch,
                                            int* __restrict__ gstart,
                                            int* __restrict__ row_start) {
    int tid = threadIdx.x;
    if (blockIdx.x < 192) {
        int idx = blockIdx.x * 256 + tid;
        if (idx < 256 * 128) {
            int k = idx >> 7, n = idx & 127;
            Wt1[n * 256 + k] = f2bf(W1[idx]);
        } else if (idx < 256 * 128 + 128 * 128) {
            int j = idx - 256 * 128;
            int k = j >> 7, n = j & 127;
            Wt2[n * 128 + k] = f2bf(W2[j]);
        }
        if (idx <= NBKT) gcur[idx] = 0;
        if (idx == 0) row_start[N_NODES] = E_TOT;
    } else {
        int i = (blockIdx.x - 192) * 256 + tid;
        if (i >= N_NODES) return;
        int b  = batch[i];
        int bp = (i == 0) ? -1 : batch[i - 1];
        for (int g = bp + 1; g <= b; g++) gstart[g] = i;
        if (i == N_NODES - 1) {
            for (int g = b + 1; g <= N_GRAPHS; g++) gstart[g] = N_NODES;
        }
    }
}

// ---------------------------------------------------------------------------
// Fused dispatch: blocks 0..NBG1-1 run layer-1 GEMM (fp32 A, K=256) with
// fused alpha epilogue; blocks NBG1.. run bin_scatter (radix partition P3).
// Independent work -> real overlap on one stream. Shared LDS union (27.6 KB).
// ---------------------------------------------------------------------------
__global__ __launch_bounds__(256) void gemm1_scatter(const float* __restrict__ A,
                                                     const ushort* __restrict__ Wt,
                                                     ushort* __restrict__ Cbf,
                                                     const float* __restrict__ a_sv,
                                                     const float* __restrict__ a_dv,
                                                     float* __restrict__ alpha_s,
                                                     float* __restrict__ alpha_d,
                                                     const int* __restrict__ edge_src,
                                                     const int* __restrict__ edge_dst,
                                                     int* __restrict__ gcur,
                                                     uint* __restrict__ staged) {
    __shared__ char smem[27648];
    int tid = threadIdx.x;

    if (blockIdx.x < NBG1) {
        // ---------------- GEMM path (K=256, fp32 A) ----------------
        constexpr int K = 256, KC = 64, AP = 72;
        ushort* As = (ushort*)smem;                 //  9216 B
        ushort* Bs = (ushort*)(smem + 9216);        // 18432 B
        int lane = tid & 63;
        int wv = tid >> 6;
        int mrow = lane & 15;
        int quad = lane >> 4;
        int row0 = blockIdx.x * 64;
        int M = N_NODES;

        f32x4 acc[8];
#pragma unroll
        for (int t = 0; t < 8; t++) acc[t] = (f32x4){0.f, 0.f, 0.f, 0.f};

        for (int k0 = 0; k0 < K; k0 += KC) {
#pragma unroll
            for (int p = 0; p < 2; p++) {
                int c = p * 256 + tid;
                int r = c >> 3;
                int kk = (c & 7) * 8;
                int grow = row0 + r;
                float4 v0 = make_float4(0.f, 0.f, 0.f, 0.f);
                float4 v1 = v0;
                if (grow < M) {
                    const float* src = &A[(size_t)grow * K + k0 + kk];
                    v0 = *(const float4*)src;
                    v1 = *(const float4*)(src + 4);
                }
                uint4 w;
                w.x = (uint)f2bf(v0.x) | ((uint)f2bf(v0.y) << 16);
                w.y = (uint)f2bf(v0.z) | ((uint)f2bf(v0.w) << 16);
                w.z = (uint)f2bf(v1.x) | ((uint)f2bf(v1.y) << 16);
                w.w = (uint)f2bf(v1.z) | ((uint)f2bf(v1.w) << 16);
                *(uint4*)&As[r * AP + kk] = w;
            }
#pragma unroll
            for (int p = 0; p < 4; p++) {
                int c = p * 256 + tid;
                int n = c >> 3;
                int kk = (c & 7) * 8;
                uint4 v = *(const uint4*)&Wt[(size_t)n * K + k0 + kk];
                *(uint4*)&Bs[n * AP + kk] = v;
            }
            __syncthreads();

            const ushort* arow = &As[(wv * 16 + mrow) * AP + quad * 8];
            const ushort* brow = &Bs[mrow * AP + quad * 8];
#pragma unroll
            for (int ks = 0; ks < KC; ks += 32) {
                bf16x8 a = *(const bf16x8*)&arow[ks];
#pragma unroll
                for (int t = 0; t < 8; t++) {
                    bf16x8 b = *(const bf16x8*)&brow[t * 16 * AP + ks];
                    acc[t] = __builtin_amdgcn_mfma_f32_16x16x32_bf16(a, b, acc[t], 0, 0, 0);
                }
            }
            __syncthreads();
        }

        float as_r[8], ad_r[8];
#pragma unroll
        for (int t = 0; t < 8; t++) {
            int col = t * 16 + mrow;
            as_r[t] = a_sv[col];
            ad_r[t] = a_dv[col];
        }
#pragma unroll
        for (int r = 0; r < 4; r++) {
            float ps = 0.f, pd = 0.f;
#pragma unroll
            for (int t = 0; t < 8; t++) {
                ps = fmaf(acc[t][r], as_r[t], ps);
                pd = fmaf(acc[t][r], ad_r[t], pd);
            }
#pragma unroll
            for (int o = 1; o < 16; o <<= 1) {
                ps += __shfl_xor(ps, o, 64);
                pd += __shfl_xor(pd, o, 64);
            }
            int row = row0 + wv * 16 + quad * 4 + r;
            if (mrow == 0 && row < M) {
                alpha_s[row] = ps;
                alpha_d[row] = pd;
            }
        }
#pragma unroll
        for (int t = 0; t < 8; t++) {
#pragma unroll
            for (int r = 0; r < 4; r++) {
                int row = row0 + wv * 16 + quad * 4 + r;
                if (row < M)
                    Cbf[(size_t)row * HID + t * 16 + mrow] = f2bf(acc[t][r]);
            }
        }
    } else {
        // ---------------- bin_scatter path ----------------
        int* hist    = (int*)smem;
        int* scan_s  = hist + 256;
        int* base_l  = scan_s + 256;
        int* cur     = base_l + 256;
        int* runbase = cur + 256;
        uint* vals   = (uint*)(runbase + 256);    // 16 KB

        int e0 = (blockIdx.x - NBG1) * CHUNK3;
        int cnt = min(CHUNK3, E_TOT - e0);

        hist[tid] = 0;
        __syncthreads();
        for (int i = tid; i < cnt; i += 256) {
            int e = e0 + i;
            int d = (e < N_EDGES) ? edge_dst[e] : (e - N_EDGES);
            atomicAdd(&hist[d >> 8], 1);
        }
        __syncthreads();
        int v = hist[tid];
        scan_s[tid] = v;
        __syncthreads();
        for (int off = 1; off < 256; off <<= 1) {
            int t = (tid >= off) ? scan_s[tid - off] : 0;
            __syncthreads();
            scan_s[tid] += t;
            __syncthreads();
        }
        base_l[tid] = scan_s[tid] - v;
        cur[tid] = scan_s[tid] - v;
        __syncthreads();
        for (int i = tid; i < cnt; i += 256) {
            int e = e0 + i;
            int s, d;
            if (e < N_EDGES) { s = edge_src[e]; d = edge_dst[e]; }
            else             { s = d = e - N_EDGES; }
            int p = atomicAdd(&cur[d >> 8], 1);
            vals[p] = ((uint)(d >> 8) << 24) | ((uint)s << 8) | (uint)(d & 255);
        }
        __syncthreads();
        if (tid < NBKT && hist[tid] > 0) runbase[tid] = atomicAdd(&gcur[tid], hist[tid]);
        __syncthreads();
        for (int i = tid; i < cnt; i += 256) {
            uint v2 = vals[i];
            int b = (int)(v2 >> 24);
            int idx = runbase[b] + (i - base_l[b]);
            if (idx < CAPB) staged[b * CAPB + idx] = v2;
        }
    }
}

// ---------------------------------------------------------------------------
// P4: one block per bucket; inline bucket scan (196 vals) + per-node CSR.
// ---------------------------------------------------------------------------
__global__ __launch_bounds__(256) void bucket_build(const uint* __restrict__ staged,
                                                    const int* __restrict__ gcur,
                                                    int* __restrict__ row_start,
                                                    ushort* __restrict__ csr_src) {
    __shared__ int hist[256], scan_s[256], base_l[256];
    __shared__ int sBase, sCnt;
    __shared__ uint lv[CAPB];
    int tid = threadIdx.x;
    int b = blockIdx.x;

    // Inline exclusive scan of bucket counts to get this bucket's base
    int v = (tid < NBKT) ? min(gcur[tid], CAPB) : 0;
    scan_s[tid] = v;
    __syncthreads();
    for (int off = 1; off < 256; off <<= 1) {
        int t = (tid >= off) ? scan_s[tid - off] : 0;
        __syncthreads();
        scan_s[tid] += t;
        __syncthreads();
    }
    if (tid == b) { sBase = scan_s[tid] - v; sCnt = v; }
    __syncthreads();
    int base = sBase;
    int cnt = sCnt;

    hist[tid] = 0;
    __syncthreads();
    for (int i = tid; i < cnt; i += 256) {
        uint v2 = staged[b * CAPB + i];
        lv[i] = v2;
        atomicAdd(&hist[v2 & 255], 1);
    }
    __syncthreads();
    int v0 = hist[tid];
    scan_s[tid] = v0;
    __syncthreads();
    for (int off = 1; off < 256; off <<= 1) {
        int t = (tid >= off) ? scan_s[tid - off] : 0;
        __syncthreads();
        scan_s[tid] += t;
        __syncthreads();
    }
    int excl = scan_s[tid] - v0;
    base_l[tid] = excl;
    int node = b * 256 + tid;
    if (node < N_NODES) row_start[node] = base + excl;
    __syncthreads();
    for (int i = tid; i < cnt; i += 256) {
        uint v2 = lv[i];
        int pos = base + atomicAdd(&base_l[v2 & 255], 1);
        csr_src[pos] = (ushort)((v2 >> 8) & 0xFFFFu);
    }
}

// ---------------------------------------------------------------------------
// Layer-2 BF16 MFMA GEMM (bf16 A, K=128) + fused alpha epilogue.
// ---------------------------------------------------------------------------
__global__ __launch_bounds__(256) void gemm_mfma2(const ushort* __restrict__ A,
                                                  const ushort* __restrict__ Wt,
                                                  ushort* __restrict__ Cbf,
                                                  const float* __restrict__ a_sv,
                                                  const float* __restrict__ a_dv,
                                                  float* __restrict__ alpha_s,
                                                  float* __restrict__ alpha_d) {
    constexpr int K = 128, KC = 64, AP = 72;
    __shared__ ushort As[64 * AP];
    __shared__ ushort Bs[128 * AP];
    int tid = threadIdx.x;
    int lane = tid & 63;
    int wv = tid >> 6;
    int mrow = lane & 15;
    int quad = lane >> 4;
    int row0 = blockIdx.x * 64;
    int M = N_NODES;

    f32x4 acc[8];
#pragma unroll
    for (int t = 0; t < 8; t++) acc[t] = (f32x4){0.f, 0.f, 0.f, 0.f};

    for (int k0 = 0; k0 < K; k0 += KC) {
#pragma unroll
        for (int p = 0; p < 2; p++) {
            int c = p * 256 + tid;
            int r = c >> 3;
            int kk = (c & 7) * 8;
            int grow = row0 + r;
            uint4 v = make_uint4(0, 0, 0, 0);
            if (grow < M) v = *(const uint4*)&A[(size_t)grow * K + k0 + kk];
            *(uint4*)&As[r * AP + kk] = v;
        }
#pragma unroll
        for (int p = 0; p < 4; p++) {
            int c = p * 256 + tid;
            int n = c >> 3;
            int kk = (c & 7) * 8;
            uint4 v = *(const uint4*)&Wt[(size_t)n * K + k0 + kk];
            *(uint4*)&Bs[n * AP + kk] = v;
        }
        __syncthreads();

        const ushort* arow = &As[(wv * 16 + mrow) * AP + quad * 8];
        const ushort* brow = &Bs[mrow * AP + quad * 8];
#pragma unroll
        for (int ks = 0; ks < KC; ks += 32) {
            bf16x8 a = *(const bf16x8*)&arow[ks];
#pragma unroll
            for (int t = 0; t < 8; t++) {
                bf16x8 b = *(const bf16x8*)&brow[t * 16 * AP + ks];
                acc[t] = __builtin_amdgcn_mfma_f32_16x16x32_bf16(a, b, acc[t], 0, 0, 0);
            }
        }
        __syncthreads();
    }

    float as_r[8], ad_r[8];
#pragma unroll
    for (int t = 0; t < 8; t++) {
        int col = t * 16 + mrow;
        as_r[t] = a_sv[col];
        ad_r[t] = a_dv[col];
    }
#pragma unroll
    for (int r = 0; r < 4; r++) {
        float ps = 0.f, pd = 0.f;
#pragma unroll
        for (int t = 0; t < 8; t++) {
            ps = fmaf(acc[t][r], as_r[t], ps);
            pd = fmaf(acc[t][r], ad_r[t], pd);
        }
#pragma unroll
        for (int o = 1; o < 16; o <<= 1) {
            ps += __shfl_xor(ps, o, 64);
            pd += __shfl_xor(pd, o, 64);
        }
        int row = row0 + wv * 16 + quad * 4 + r;
        if (mrow == 0 && row < M) {
            alpha_s[row] = ps;
            alpha_d[row] = pd;
        }
    }
#pragma unroll
    for (int t = 0; t < 8; t++) {
#pragma unroll
        for (int r = 0; r < 4; r++) {
            int row = row0 + wv * 16 + quad * 4 + r;
            if (row < M)
                Cbf[(size_t)row * HID + t * 16 + mrow] = f2bf(acc[t][r]);
        }
    }
}

// ---------------------------------------------------------------------------
// GAT aggregation v3 (R8 winner): one node per 16-lane quarter.
// ---------------------------------------------------------------------------
__global__ __launch_bounds__(256) void gat_aggregate(const ushort* __restrict__ hbf,
                                                     const float* __restrict__ alpha_s,
                                                     const float* __restrict__ alpha_d,
                                                     const int* __restrict__ row_start,
                                                     const ushort* __restrict__ csr_src,
                                                     const float* __restrict__ bias,
                                                     ushort* __restrict__ outbf) {
    __shared__ float exv[4][4][72];
    __shared__ uint  sov[4][4][72];
    int wv = threadIdx.x >> 6;
    int lane = threadIdx.x & 63;
    int q = lane >> 4;
    int l = lane & 15;
    int n = blockIdx.x * 16 + wv * 4 + q;
    float* exq = exv[wv][q];
    uint*  soq = sov[wv][q];

    int beg = row_start[n];
    int deg = row_start[n + 1] - beg;
    float adn = alpha_d[n];
    int c8 = l * 8;
    const char* hbase = (const char*)hbf + c8 * 2;

    float a[8];
#pragma unroll
    for (int i = 0; i < 8; i++) a[i] = 0.f;
    float ssum = 0.f;

    for (int c0 = 0; c0 < deg; c0 += 64) {
        int cnt = min(64, deg - c0);
        for (int k = l; k < 72; k += 16) {
            if (k < cnt) {
                int s = csr_src[beg + c0 + k];
                float e = alpha_s[s] + adn;
                e = (e > 0.f) ? e : e * NEG_SLOPE;
                float ex = __expf(e);
                exq[k] = ex;
                soq[k] = (uint)s * (HID * 2);
                ssum += ex;
            } else {
                exq[k] = 0.f;
                soq[k] = 0u;
            }
        }
        __builtin_amdgcn_wave_barrier();
        int cm = cnt;
        cm = max(cm, __shfl_xor(cm, 16, 64));
        cm = max(cm, __shfl_xor(cm, 32, 64));
        for (int t0 = 0; t0 < cm; t0 += 8) {
            uint off[8]; uint4 v[8]; float w[8];
#pragma unroll
            for (int b = 0; b < 8; b++) off[b] = soq[t0 + b];
#pragma unroll
            for (int b = 0; b < 8; b++) v[b] = *(const uint4*)(hbase + off[b]);
#pragma unroll
            for (int b = 0; b < 8; b++) w[b] = exq[t0 + b];
#pragma unroll
            for (int b = 0; b < 8; b++) {
                a[0] = fmaf(w[b], bfbits2f(v[b].x << 16), a[0]);
                a[1] = fmaf(w[b], bfbits2f(v[b].x & 0xffff0000u), a[1]);
                a[2] = fmaf(w[b], bfbits2f(v[b].y << 16), a[2]);
                a[3] = fmaf(w[b], bfbits2f(v[b].y & 0xffff0000u), a[3]);
                a[4] = fmaf(w[b], bfbits2f(v[b].z << 16), a[4]);
                a[5] = fmaf(w[b], bfbits2f(v[b].z & 0xffff0000u), a[5]);
                a[6] = fmaf(w[b], bfbits2f(v[b].w << 16), a[6]);
                a[7] = fmaf(w[b], bfbits2f(v[b].w & 0xffff0000u), a[7]);
            }
        }
        __builtin_amdgcn_wave_barrier();
    }

    ssum += __shfl_xor(ssum, 1, 64);
    ssum += __shfl_xor(ssum, 2, 64);
    ssum += __shfl_xor(ssum, 4, 64);
    ssum += __shfl_xor(ssum, 8, 64);
    float inv = 1.f / ssum;
    float4 b0 = *(const float4*)&bias[c8];
    float4 b1 = *(const float4*)&bias[c8 + 4];
    float o0 = fmaxf(fmaf(a[0], inv, b0.x), 0.f);
    float o1 = fmaxf(fmaf(a[1], inv, b0.y), 0.f);
    float o2 = fmaxf(fmaf(a[2], inv, b0.z), 0.f);
    float o3 = fmaxf(fmaf(a[3], inv, b0.w), 0.f);
    float o4 = fmaxf(fmaf(a[4], inv, b1.x), 0.f);
    float o5 = fmaxf(fmaf(a[5], inv, b1.y), 0.f);
    float o6 = fmaxf(fmaf(a[6], inv, b1.z), 0.f);
    float o7 = fmaxf(fmaf(a[7], inv, b1.w), 0.f);
    uint4 pk;
    pk.x = (uint)f2bf(o0) | ((uint)f2bf(o1) << 16);
    pk.y = (uint)f2bf(o2) | ((uint)f2bf(o3) << 16);
    pk.z = (uint)f2bf(o4) | ((uint)f2bf(o5) << 16);
    pk.w = (uint)f2bf(o6) | ((uint)f2bf(o7) << 16);
    *(uint4*)&outbf[(size_t)n * HID + c8] = pk;
}

// ---------------------------------------------------------------------------
// Mean pool per graph: partials (no atomics, no memset) + classifier
// ---------------------------------------------------------------------------
__global__ __launch_bounds__(128) void pool_partial(const ushort* __restrict__ h,
                                                    const int* __restrict__ gstart,
                                                    float* __restrict__ pool_p) {
    int g = blockIdx.x;
    int slice = blockIdx.y;     // 0..15
    int d = threadIdx.x;
    int beg = gstart[g], end = gstart[g + 1];
    float acc = 0.f;
    for (int i = beg + slice; i < end; i += 16)
        acc += bfbits2f(((uint)h[(size_t)i * HID + d]) << 16);
    pool_p[(g * 16 + slice) * HID + d] = acc;
}

__global__ __launch_bounds__(128) void classify(const float* __restrict__ pool_p,
                                                const int* __restrict__ gstart,
                                                const float* __restrict__ Wc,
                                                const float* __restrict__ bc,
                                                float* __restrict__ out) {
    int g = blockIdx.x;
    int d = threadIdx.x;
    float s = 0.f;
#pragma unroll
    for (int sl = 0; sl < 16; sl++)
        s += pool_p[(g * 16 + sl) * HID + d];
    float cnt = (float)(gstart[g + 1] - gstart[g]);
    float p = (s / fmaxf(cnt, 1.f)) * Wc[d];
    __shared__ float red[2];
    for (int o = 32; o; o >>= 1) p += __shfl_xor(p, o, 64);
    if ((d & 63) == 0) red[d >> 6] = p;
    __syncthreads();
    if (d == 0) {
        float t = red[0] + red[1] + bc[0];
        out[g] = 1.f / (1.f + expf(-t));
    }
}

// ---------------------------------------------------------------------------
extern "C" void kernel_launch(void* const* d_in, const int* in_sizes, int n_in,
                              void* d_out, int out_size, void* d_ws, size_t ws_size,
                              hipStream_t stream) {
    const float* x     = (const float*)d_in[0];
    const int*   ei    = (const int*)d_in[1];
    const int*   batch = (const int*)d_in[2];
    const float* W1    = (const float*)d_in[3];
    const float* as1   = (const float*)d_in[4];
    const float* ad1   = (const float*)d_in[5];
    const float* b1    = (const float*)d_in[6];
    const float* W2    = (const float*)d_in[7];
    const float* as2   = (const float*)d_in[8];
    const float* ad2   = (const float*)d_in[9];
    const float* b2    = (const float*)d_in[10];
    const float* Wc    = (const float*)d_in[11];
    const float* bc    = (const float*)d_in[12];
    float* out = (float*)d_out;

    char* p = (char*)d_ws;
    auto alloc = [&](size_t bytes) {
        void* r = (void*)p;
        p += (bytes + 255) & ~(size_t)255;
        return r;
    };
    ushort* h0     = (ushort*)alloc((size_t)N_NODES * HID * 2);   // gemm1 out / agg2 out
    ushort* h1     = (ushort*)alloc((size_t)N_NODES * HID * 2);   // agg1 out
    ushort* h2     = (ushort*)alloc((size_t)N_NODES * HID * 2);   // gemm2 out
    float*  alS    = (float*)alloc((size_t)N_NODES * 4);
    float*  alD    = (float*)alloc((size_t)N_NODES * 4);
    uint*   staged = (uint*)alloc((size_t)NBKT * CAPB * 4);       // 4.8 MB
    ushort* csr    = (ushort*)alloc((size_t)E_TOT * 2);           // 1.7 MB
    int*    rstart = (int*)alloc((size_t)(N_NODES + 1) * 4);
    int*    gcur   = (int*)alloc((NBKT + 1) * 4);
    int*    gstart = (int*)alloc((N_GRAPHS + 1) * 4);
    float*  pool_p = (float*)alloc((size_t)N_GRAPHS * 16 * HID * 4);  // 512 KB
    ushort* Wt1    = (ushort*)alloc((size_t)128 * 256 * 2);
    ushort* Wt2    = (ushort*)alloc((size_t)128 * 128 * 2);

    const int* edge_src = ei;
    const int* edge_dst = ei + N_EDGES;

    // 1. Prep (weights + gcur + graph bounds + row_start[N])
    prep<<<388, 256, 0, stream>>>(W1, W2, Wt1, Wt2, gcur, batch, gstart, rstart);
    // 2. Layer-1 GEMM || radix scatter (independent -> overlapped)
    gemm1_scatter<<<NBG1 + NB3, 256, 0, stream>>>(
        x, Wt1, h0, as1, ad1, alS, alD, edge_src, edge_dst, gcur, staged);
    // 3. CSR finalize (inline bucket scan)
    bucket_build<<<NBKT, 256, 0, stream>>>(staged, gcur, rstart, csr);
    // 4. Layer-1 aggregate
    gat_aggregate<<<N_NODES / 16, 256, 0, stream>>>(h0, alS, alD, rstart, csr, b1, h1);
    // 5. Layer-2 GEMM
    gemm_mfma2<<<NBG1, 256, 0, stream>>>(h1, Wt2, h2, as2, ad2, alS, alD);
    // 6. Layer-2 aggregate
    gat_aggregate<<<N_NODES / 16, 256, 0, stream>>>(h2, alS, alD, rstart, csr, b2, h0);
    // 7-8. Pool + classify
    pool_partial<<<dim3(N_GRAPHS, 16), HID, 0, stream>>>(h0, gstart, pool_p);
    classify<<<N_GRAPHS, HID, 0, stream>>>(pool_p, gstart, Wc, bc, out);
}

// Round 10
// 205.192 us; speedup vs baseline: 1.8519x; 1.0851x over previous
//
#include <hip/hip_runtime.h>
#include <hip/hip_bf16.h>
#include <math.h>

// Problem constants (from reference)
#define N_NODES 50000
#define N_EDGES 800000
#define E_TOT   (N_EDGES + N_NODES)   // edges + self loops = 850000
#define HID     128
#define N_GRAPHS 64
#define NEG_SLOPE 0.2f

// Radix partition params
#define NBKT 196                      // buckets of 256 dst nodes
#define CAPB 6144                     // fixed bucket capacity (mean 4337, +27 sigma)
#define CHUNK3 4096
#define NB3  ((E_TOT + CHUNK3 - 1) / CHUNK3)    // 208
#define NBG1 ((N_NODES + 63) / 64)              // 782 gemm blocks

typedef __attribute__((ext_vector_type(8))) short bf16x8;
typedef __attribute__((ext_vector_type(4))) float f32x4;
typedef __attribute__((ext_vector_type(2))) float f32x2;

__device__ __forceinline__ ushort f2bf(float f) {
    union { float f; uint u; } x; x.f = f;
    uint r = x.u + 0x7fffu + ((x.u >> 16) & 1u);   // round-to-nearest-even
    return (ushort)(r >> 16);
}
__device__ __forceinline__ float bfbits2f(uint bits_hi) {
    union { uint u; float f; } x; x.u = bits_hi;
    return x.f;
}

// ---------------------------------------------------------------------------
// Prep: weight convert+transpose, gcur zero, graph bounds, row_start[N]=E_TOT.
// ---------------------------------------------------------------------------
__global__ __launch_bounds__(256) void prep(const float* __restrict__ W1,
                                            const float* __restrict__ W2,
                                            ushort* __restrict__ Wt1,
                                            ushort* __restrict__ Wt2,
                                            int* __restrict__ gcur,
                                            const int* __restrict__ batch,
                                            int* __restrict__ gstart,
                                            int* __restrict__ row_start) {
    int tid = threadIdx.x;
    if (blockIdx.x < 192) {
        int idx = blockIdx.x * 256 + tid;
        if (idx < 256 * 128) {
            int k = idx >> 7, n = idx & 127;
            Wt1[n * 256 + k] = f2bf(W1[idx]);
        } else if (idx < 256 * 128 + 128 * 128) {
            int j = idx - 256 * 128;
            int k = j >> 7, n = j & 127;
            Wt2[n * 128 + k] = f2bf(W2[j]);
        }
        if (idx <= NBKT) gcur[idx] = 0;
        if (idx == 0) row_start[N_NODES] = E_TOT;
    } else {
        int i = (blockIdx.x - 192) * 256 + tid;
        if (i >= N_NODES) return;
        int b  = batch[i];
        int bp = (i == 0) ? -1 : batch[i - 1];
        for (int g = bp + 1; g <= b; g++) gstart[g] = i;
        if (i == N_NODES - 1) {
            for (int g = b + 1; g <= N_GRAPHS; g++) gstart[g] = N_NODES;
        }
    }
}

// ---------------------------------------------------------------------------
// Fused dispatch: blocks 0..NBG1-1 layer-1 GEMM (fp32 A, K=256, fp8 C shadow
// + fused alpha); blocks NBG1.. bin_scatter. Shared 27.6 KB LDS union.
// ---------------------------------------------------------------------------
__global__ __launch_bounds__(256) void gemm1_scatter(const float* __restrict__ A,
                                                     const ushort* __restrict__ Wt,
                                                     unsigned char* __restrict__ C8,
                                                     const float* __restrict__ a_sv,
                                                     const float* __restrict__ a_dv,
                                                     float* __restrict__ alpha_s,
                                                     float* __restrict__ alpha_d,
                                                     const int* __restrict__ edge_src,
                                                     const int* __restrict__ edge_dst,
                                                     int* __restrict__ gcur,
                                                     uint* __restrict__ staged) {
    __shared__ char smem[27648];
    int tid = threadIdx.x;

    if (blockIdx.x < NBG1) {
        constexpr int K = 256, KC = 64, AP = 72;
        ushort* As = (ushort*)smem;
        ushort* Bs = (ushort*)(smem + 9216);
        int lane = tid & 63;
        int wv = tid >> 6;
        int mrow = lane & 15;
        int quad = lane >> 4;
        int row0 = blockIdx.x * 64;
        int M = N_NODES;

        f32x4 acc[8];
#pragma unroll
        for (int t = 0; t < 8; t++) acc[t] = (f32x4){0.f, 0.f, 0.f, 0.f};

        for (int k0 = 0; k0 < K; k0 += KC) {
#pragma unroll
            for (int p = 0; p < 2; p++) {
                int c = p * 256 + tid;
                int r = c >> 3;
                int kk = (c & 7) * 8;
                int grow = row0 + r;
                float4 v0 = make_float4(0.f, 0.f, 0.f, 0.f);
                float4 v1 = v0;
                if (grow < M) {
                    const float* src = &A[(size_t)grow * K + k0 + kk];
                    v0 = *(const float4*)src;
                    v1 = *(const float4*)(src + 4);
                }
                uint4 w;
                w.x = (uint)f2bf(v0.x) | ((uint)f2bf(v0.y) << 16);
                w.y = (uint)f2bf(v0.z) | ((uint)f2bf(v0.w) << 16);
                w.z = (uint)f2bf(v1.x) | ((uint)f2bf(v1.y) << 16);
                w.w = (uint)f2bf(v1.z) | ((uint)f2bf(v1.w) << 16);
                *(uint4*)&As[r * AP + kk] = w;
            }
#pragma unroll
            for (int p = 0; p < 4; p++) {
                int c = p * 256 + tid;
                int n = c >> 3;
                int kk = (c & 7) * 8;
                uint4 v = *(const uint4*)&Wt[(size_t)n * K + k0 + kk];
                *(uint4*)&Bs[n * AP + kk] = v;
            }
            __syncthreads();

            const ushort* arow = &As[(wv * 16 + mrow) * AP + quad * 8];
            const ushort* brow = &Bs[mrow * AP + quad * 8];
#pragma unroll
            for (int ks = 0; ks < KC; ks += 32) {
                bf16x8 a = *(const bf16x8*)&arow[ks];
#pragma unroll
                for (int t = 0; t < 8; t++) {
                    bf16x8 b = *(const bf16x8*)&brow[t * 16 * AP + ks];
                    acc[t] = __builtin_amdgcn_mfma_f32_16x16x32_bf16(a, b, acc[t], 0, 0, 0);
                }
            }
            __syncthreads();
        }

        float as_r[8], ad_r[8];
#pragma unroll
        for (int t = 0; t < 8; t++) {
            int col = t * 16 + mrow;
            as_r[t] = a_sv[col];
            ad_r[t] = a_dv[col];
        }
#pragma unroll
        for (int r = 0; r < 4; r++) {
            float ps = 0.f, pd = 0.f;
#pragma unroll
            for (int t = 0; t < 8; t++) {
                ps = fmaf(acc[t][r], as_r[t], ps);
                pd = fmaf(acc[t][r], ad_r[t], pd);
            }
#pragma unroll
            for (int o = 1; o < 16; o <<= 1) {
                ps += __shfl_xor(ps, o, 64);
                pd += __shfl_xor(pd, o, 64);
            }
            int row = row0 + wv * 16 + quad * 4 + r;
            if (mrow == 0 && row < M) {
                alpha_s[row] = ps;
                alpha_d[row] = pd;
            }
        }
        // fp8 e4m3 shadow only (gathers read fp8; no bf16 copy needed)
#pragma unroll
        for (int t = 0; t < 8; t++) {
#pragma unroll
            for (int r = 0; r < 4; r++) {
                int row = row0 + wv * 16 + quad * 4 + r;
                if (row < M) {
                    float vv = acc[t][r];
                    uint p8 = (uint)__builtin_amdgcn_cvt_pk_fp8_f32(vv, vv, 0, false);
                    C8[(size_t)row * HID + t * 16 + mrow] = (unsigned char)(p8 & 0xFF);
                }
            }
        }
    } else {
        int* hist    = (int*)smem;
        int* scan_s  = hist + 256;
        int* base_l  = scan_s + 256;
        int* cur     = base_l + 256;
        int* runbase = cur + 256;
        uint* vals   = (uint*)(runbase + 256);

        int e0 = (blockIdx.x - NBG1) * CHUNK3;
        int cnt = min(CHUNK3, E_TOT - e0);

        hist[tid] = 0;
        __syncthreads();
        for (int i = tid; i < cnt; i += 256) {
            int e = e0 + i;
            int d = (e < N_EDGES) ? edge_dst[e] : (e - N_EDGES);
            atomicAdd(&hist[d >> 8], 1);
        }
        __syncthreads();
        int v = hist[tid];
        scan_s[tid] = v;
        __syncthreads();
        for (int off = 1; off < 256; off <<= 1) {
            int t = (tid >= off) ? scan_s[tid - off] : 0;
            __syncthreads();
            scan_s[tid] += t;
            __syncthreads();
        }
        base_l[tid] = scan_s[tid] - v;
        cur[tid] = scan_s[tid] - v;
        __syncthreads();
        for (int i = tid; i < cnt; i += 256) {
            int e = e0 + i;
            int s, d;
            if (e < N_EDGES) { s = edge_src[e]; d = edge_dst[e]; }
            else             { s = d = e - N_EDGES; }
            int p = atomicAdd(&cur[d >> 8], 1);
            vals[p] = ((uint)(d >> 8) << 24) | ((uint)s << 8) | (uint)(d & 255);
        }
        __syncthreads();
        if (tid < NBKT && hist[tid] > 0) runbase[tid] = atomicAdd(&gcur[tid], hist[tid]);
        __syncthreads();
        for (int i = tid; i < cnt; i += 256) {
            uint v2 = vals[i];
            int b = (int)(v2 >> 24);
            int idx = runbase[b] + (i - base_l[b]);
            if (idx < CAPB) staged[b * CAPB + idx] = v2;
        }
    }
}

// ---------------------------------------------------------------------------
// P4: one block per bucket; inline bucket scan + per-node CSR.
// ---------------------------------------------------------------------------
__global__ __launch_bounds__(256) void bucket_build(const uint* __restrict__ staged,
                                                    const int* __restrict__ gcur,
                                                    int* __restrict__ row_start,
                                                    ushort* __restrict__ csr_src) {
    __shared__ int hist[256], scan_s[256], base_l[256];
    __shared__ int sBase, sCnt;
    __shared__ uint lv[CAPB];
    int tid = threadIdx.x;
    int b = blockIdx.x;

    int v = (tid < NBKT) ? min(gcur[tid], CAPB) : 0;
    scan_s[tid] = v;
    __syncthreads();
    for (int off = 1; off < 256; off <<= 1) {
        int t = (tid >= off) ? scan_s[tid - off] : 0;
        __syncthreads();
        scan_s[tid] += t;
        __syncthreads();
    }
    if (tid == b) { sBase = scan_s[tid] - v; sCnt = v; }
    __syncthreads();
    int base = sBase;
    int cnt = sCnt;

    hist[tid] = 0;
    __syncthreads();
    for (int i = tid; i < cnt; i += 256) {
        uint v2 = staged[b * CAPB + i];
        lv[i] = v2;
        atomicAdd(&hist[v2 & 255], 1);
    }
    __syncthreads();
    int v0 = hist[tid];
    scan_s[tid] = v0;
    __syncthreads();
    for (int off = 1; off < 256; off <<= 1) {
        int t = (tid >= off) ? scan_s[tid - off] : 0;
        __syncthreads();
        scan_s[tid] += t;
        __syncthreads();
    }
    int excl = scan_s[tid] - v0;
    base_l[tid] = excl;
    int node = b * 256 + tid;
    if (node < N_NODES) row_start[node] = base + excl;
    __syncthreads();
    for (int i = tid; i < cnt; i += 256) {
        uint v2 = lv[i];
        int pos = base + atomicAdd(&base_l[v2 & 255], 1);
        csr_src[pos] = (ushort)((v2 >> 8) & 0xFFFFu);
    }
}

// ---------------------------------------------------------------------------
// Layer-2 GEMM (bf16 A, K=128): fp8 C shadow + fused alpha.
// ---------------------------------------------------------------------------
__global__ __launch_bounds__(256) void gemm_mfma2(const ushort* __restrict__ A,
                                                  const ushort* __restrict__ Wt,
                                                  unsigned char* __restrict__ C8,
                                                  const float* __restrict__ a_sv,
                                                  const float* __restrict__ a_dv,
                                                  float* __restrict__ alpha_s,
                                                  float* __restrict__ alpha_d) {
    constexpr int K = 128, KC = 64, AP = 72;
    __shared__ ushort As[64 * AP];
    __shared__ ushort Bs[128 * AP];
    int tid = threadIdx.x;
    int lane = tid & 63;
    int wv = tid >> 6;
    int mrow = lane & 15;
    int quad = lane >> 4;
    int row0 = blockIdx.x * 64;
    int M = N_NODES;

    f32x4 acc[8];
#pragma unroll
    for (int t = 0; t < 8; t++) acc[t] = (f32x4){0.f, 0.f, 0.f, 0.f};

    for (int k0 = 0; k0 < K; k0 += KC) {
#pragma unroll
        for (int p = 0; p < 2; p++) {
            int c = p * 256 + tid;
            int r = c >> 3;
            int kk = (c & 7) * 8;
            int grow = row0 + r;
            uint4 v = make_uint4(0, 0, 0, 0);
            if (grow < M) v = *(const uint4*)&A[(size_t)grow * K + k0 + kk];
            *(uint4*)&As[r * AP + kk] = v;
        }
#pragma unroll
        for (int p = 0; p < 4; p++) {
            int c = p * 256 + tid;
            int n = c >> 3;
            int kk = (c & 7) * 8;
            uint4 v = *(const uint4*)&Wt[(size_t)n * K + k0 + kk];
            *(uint4*)&Bs[n * AP + kk] = v;
        }
        __syncthreads();

        const ushort* arow = &As[(wv * 16 + mrow) * AP + quad * 8];
        const ushort* brow = &Bs[mrow * AP + quad * 8];
#pragma unroll
        for (int ks = 0; ks < KC; ks += 32) {
            bf16x8 a = *(const bf16x8*)&arow[ks];
#pragma unroll
            for (int t = 0; t < 8; t++) {
                bf16x8 b = *(const bf16x8*)&brow[t * 16 * AP + ks];
                acc[t] = __builtin_amdgcn_mfma_f32_16x16x32_bf16(a, b, acc[t], 0, 0, 0);
            }
        }
        __syncthreads();
    }

    float as_r[8], ad_r[8];
#pragma unroll
    for (int t = 0; t < 8; t++) {
        int col = t * 16 + mrow;
        as_r[t] = a_sv[col];
        ad_r[t] = a_dv[col];
    }
#pragma unroll
    for (int r = 0; r < 4; r++) {
        float ps = 0.f, pd = 0.f;
#pragma unroll
        for (int t = 0; t < 8; t++) {
            ps = fmaf(acc[t][r], as_r[t], ps);
            pd = fmaf(acc[t][r], ad_r[t], pd);
        }
#pragma unroll
        for (int o = 1; o < 16; o <<= 1) {
            ps += __shfl_xor(ps, o, 64);
            pd += __shfl_xor(pd, o, 64);
        }
        int row = row0 + wv * 16 + quad * 4 + r;
        if (mrow == 0 && row < M) {
            alpha_s[row] = ps;
            alpha_d[row] = pd;
        }
    }
#pragma unroll
    for (int t = 0; t < 8; t++) {
#pragma unroll
        for (int r = 0; r < 4; r++) {
            int row = row0 + wv * 16 + quad * 4 + r;
            if (row < M) {
                float vv = acc[t][r];
                uint p8 = (uint)__builtin_amdgcn_cvt_pk_fp8_f32(vv, vv, 0, false);
                C8[(size_t)row * HID + t * 16 + mrow] = (unsigned char)(p8 & 0xFF);
            }
        }
    }
}

// ---------------------------------------------------------------------------
// GAT aggregation v4: R8 structure (one node per 16-lane quarter, batch-8,
// unnormalized accumulate) over the fp8 shadow: lane owns 8 cols = uint2 =
// full 128B fp8 row per quarter. Halves the per-XCD compulsory footprint.
// ---------------------------------------------------------------------------
__global__ __launch_bounds__(256) void gat_aggregate(const unsigned char* __restrict__ h8,
                                                     const float* __restrict__ alpha_s,
                                                     const float* __restrict__ alpha_d,
                                                     const int* __restrict__ row_start,
                                                     const ushort* __restrict__ csr_src,
                                                     const float* __restrict__ bias,
                                                     ushort* __restrict__ outbf) {
    __shared__ float exv[4][4][72];
    __shared__ uint  sov[4][4][72];
    int wv = threadIdx.x >> 6;
    int lane = threadIdx.x & 63;
    int q = lane >> 4;
    int l = lane & 15;
    int n = blockIdx.x * 16 + wv * 4 + q;
    float* exq = exv[wv][q];
    uint*  soq = sov[wv][q];

    int beg = row_start[n];
    int deg = row_start[n + 1] - beg;
    float adn = alpha_d[n];
    int c8 = l * 8;
    const char* hbase = (const char*)h8 + c8;

    float a[8];
#pragma unroll
    for (int i = 0; i < 8; i++) a[i] = 0.f;
    float ssum = 0.f;

    for (int c0 = 0; c0 < deg; c0 += 64) {
        int cnt = min(64, deg - c0);
        for (int k = l; k < 72; k += 16) {
            if (k < cnt) {
                int s = csr_src[beg + c0 + k];
                float e = alpha_s[s] + adn;
                e = (e > 0.f) ? e : e * NEG_SLOPE;
                float ex = __expf(e);
                exq[k] = ex;
                soq[k] = (uint)s * HID;
                ssum += ex;
            } else {
                exq[k] = 0.f;
                soq[k] = 0u;
            }
        }
        __builtin_amdgcn_wave_barrier();
        int cm = cnt;
        cm = max(cm, __shfl_xor(cm, 16, 64));
        cm = max(cm, __shfl_xor(cm, 32, 64));
        for (int t0 = 0; t0 < cm; t0 += 8) {
            uint off[8]; uint2 v[8]; float w[8];
#pragma unroll
            for (int b = 0; b < 8; b++) off[b] = soq[t0 + b];
#pragma unroll
            for (int b = 0; b < 8; b++) v[b] = *(const uint2*)(hbase + off[b]);
#pragma unroll
            for (int b = 0; b < 8; b++) w[b] = exq[t0 + b];
#pragma unroll
            for (int b = 0; b < 8; b++) {
                f32x2 p0 = __builtin_amdgcn_cvt_pk_f32_fp8((int)v[b].x, false);
                f32x2 p1 = __builtin_amdgcn_cvt_pk_f32_fp8((int)v[b].x, true);
                f32x2 p2 = __builtin_amdgcn_cvt_pk_f32_fp8((int)v[b].y, false);
                f32x2 p3 = __builtin_amdgcn_cvt_pk_f32_fp8((int)v[b].y, true);
                a[0] = fmaf(w[b], p0.x, a[0]); a[1] = fmaf(w[b], p0.y, a[1]);
                a[2] = fmaf(w[b], p1.x, a[2]); a[3] = fmaf(w[b], p1.y, a[3]);
                a[4] = fmaf(w[b], p2.x, a[4]); a[5] = fmaf(w[b], p2.y, a[5]);
                a[6] = fmaf(w[b], p3.x, a[6]); a[7] = fmaf(w[b], p3.y, a[7]);
            }
        }
        __builtin_amdgcn_wave_barrier();
    }

    ssum += __shfl_xor(ssum, 1, 64);
    ssum += __shfl_xor(ssum, 2, 64);
    ssum += __shfl_xor(ssum, 4, 64);
    ssum += __shfl_xor(ssum, 8, 64);
    float inv = 1.f / ssum;
    float4 b0 = *(const float4*)&bias[c8];
    float4 b1 = *(const float4*)&bias[c8 + 4];
    float o0 = fmaxf(fmaf(a[0], inv, b0.x), 0.f);
    float o1 = fmaxf(fmaf(a[1], inv, b0.y), 0.f);
    float o2 = fmaxf(fmaf(a[2], inv, b0.z), 0.f);
    float o3 = fmaxf(fmaf(a[3], inv, b0.w), 0.f);
    float o4 = fmaxf(fmaf(a[4], inv, b1.x), 0.f);
    float o5 = fmaxf(fmaf(a[5], inv, b1.y), 0.f);
    float o6 = fmaxf(fmaf(a[6], inv, b1.z), 0.f);
    float o7 = fmaxf(fmaf(a[7], inv, b1.w), 0.f);
    uint4 pk;
    pk.x = (uint)f2bf(o0) | ((uint)f2bf(o1) << 16);
    pk.y = (uint)f2bf(o2) | ((uint)f2bf(o3) << 16);
    pk.z = (uint)f2bf(o4) | ((uint)f2bf(o5) << 16);
    pk.w = (uint)f2bf(o6) | ((uint)f2bf(o7) << 16);
    *(uint4*)&outbf[(size_t)n * HID + c8] = pk;
}

// ---------------------------------------------------------------------------
// Mean pool per graph: partials (no atomics) + classifier
// ---------------------------------------------------------------------------
__global__ __launch_bounds__(128) void pool_partial(const ushort* __restrict__ h,
                                                    const int* __restrict__ gstart,
                                                    float* __restrict__ pool_p) {
    int g = blockIdx.x;
    int slice = blockIdx.y;
    int d = threadIdx.x;
    int beg = gstart[g], end = gstart[g + 1];
    float acc = 0.f;
    for (int i = beg + slice; i < end; i += 16)
        acc += bfbits2f(((uint)h[(size_t)i * HID + d]) << 16);
    pool_p[(g * 16 + slice) * HID + d] = acc;
}

__global__ __launch_bounds__(128) void classify(const float* __restrict__ pool_p,
                                                const int* __restrict__ gstart,
                                                const float* __restrict__ Wc,
                                                const float* __restrict__ bc,
                                                float* __restrict__ out) {
    int g = blockIdx.x;
    int d = threadIdx.x;
    float s = 0.f;
#pragma unroll
    for (int sl = 0; sl < 16; sl++)
        s += pool_p[(g * 16 + sl) * HID + d];
    float cnt = (float)(gstart[g + 1] - gstart[g]);
    float p = (s / fmaxf(cnt, 1.f)) * Wc[d];
    __shared__ float red[2];
    for (int o = 32; o; o >>= 1) p += __shfl_xor(p, o, 64);
    if ((d & 63) == 0) red[d >> 6] = p;
    __syncthreads();
    if (d == 0) {
        float t = red[0] + red[1] + bc[0];
        out[g] = 1.f / (1.f + expf(-t));
    }
}

// ---------------------------------------------------------------------------
extern "C" void kernel_launch(void* const* d_in, const int* in_sizes, int n_in,
                              void* d_out, int out_size, void* d_ws, size_t ws_size,
                              hipStream_t stream) {
    const float* x     = (const float*)d_in[0];
    const int*   ei    = (const int*)d_in[1];
    const int*   batch = (const int*)d_in[2];
    const float* W1    = (const float*)d_in[3];
    const float* as1   = (const float*)d_in[4];
    const float* ad1   = (const float*)d_in[5];
    const float* b1    = (const float*)d_in[6];
    const float* W2    = (const float*)d_in[7];
    const float* as2   = (const float*)d_in[8];
    const float* ad2   = (const float*)d_in[9];
    const float* b2    = (const float*)d_in[10];
    const float* Wc    = (const float*)d_in[11];
    const float* bc    = (const float*)d_in[12];
    float* out = (float*)d_out;

    char* p = (char*)d_ws;
    auto alloc = [&](size_t bytes) {
        void* r = (void*)p;
        p += (bytes + 255) & ~(size_t)255;
        return r;
    };
    unsigned char* h8 = (unsigned char*)alloc((size_t)N_NODES * HID); // fp8 gemm out (both layers)
    ushort* h1     = (ushort*)alloc((size_t)N_NODES * HID * 2);       // agg1 out (bf16)
    ushort* h0     = (ushort*)alloc((size_t)N_NODES * HID * 2);       // agg2 out (bf16)
    float*  alS    = (float*)alloc((size_t)N_NODES * 4);
    float*  alD    = (float*)alloc((size_t)N_NODES * 4);
    uint*   staged = (uint*)alloc((size_t)NBKT * CAPB * 4);           // 4.8 MB
    ushort* csr    = (ushort*)alloc((size_t)E_TOT * 2);               // 1.7 MB
    int*    rstart = (int*)alloc((size_t)(N_NODES + 1) * 4);
    int*    gcur   = (int*)alloc((NBKT + 1) * 4);
    int*    gstart = (int*)alloc((N_GRAPHS + 1) * 4);
    float*  pool_p = (float*)alloc((size_t)N_GRAPHS * 16 * HID * 4);
    ushort* Wt1    = (ushort*)alloc((size_t)128 * 256 * 2);
    ushort* Wt2    = (ushort*)alloc((size_t)128 * 128 * 2);

    const int* edge_src = ei;
    const int* edge_dst = ei + N_EDGES;

    // 1. Prep
    prep<<<388, 256, 0, stream>>>(W1, W2, Wt1, Wt2, gcur, batch, gstart, rstart);
    // 2. Layer-1 GEMM || radix scatter
    gemm1_scatter<<<NBG1 + NB3, 256, 0, stream>>>(
        x, Wt1, h8, as1, ad1, alS, alD, edge_src, edge_dst, gcur, staged);
    // 3. CSR finalize
    bucket_build<<<NBKT, 256, 0, stream>>>(staged, gcur, rstart, csr);
    // 4. Layer-1 aggregate (fp8 gather)
    gat_aggregate<<<N_NODES / 16, 256, 0, stream>>>(h8, alS, alD, rstart, csr, b1, h1);
    // 5. Layer-2 GEMM
    gemm_mfma2<<<NBG1, 256, 0, stream>>>(h1, Wt2, h8, as2, ad2, alS, alD);
    // 6. Layer-2 aggregate (fp8 gather)
    gat_aggregate<<<N_NODES / 16, 256, 0, stream>>>(h8, alS, alD, rstart, csr, b2, h0);
    // 7-8. Pool + classify
    pool_partial<<<dim3(N_GRAPHS, 16), HID, 0, stream>>>(h0, gstart, pool_p);
    classify<<<N_GRAPHS, HID, 0, stream>>>(pool_p, gstart, Wc, bc, out);
}